// Round 1
// baseline (295.120 us; speedup 1.0000x reference)
//
#include <hip/hip_runtime.h>
#include <math.h>

#define BSZ 2
#define LSEQ 4096
#define DM 256      // d_model
#define DI 256      // d_inner
#define DS 16       // d_state
#define DR 16       // dt_rank
#define NIN 512     // 2*DI
#define NDBC 48     // DR + 2*DS
#define NCHUNK 64
#define LCHUNK 64

__device__ __forceinline__ float sigmoid_f(float v) {
    return 1.0f / (1.0f + expf(-v));
}

// ---------------- gemm_in: xz[b,l,n] = sum_c x[b,c,l] * W_in[c,n] ----------------
// A is transposed access (x is (B,C,L), contiguous in l=m). 128x128 tile, 8x8/thread.
__global__ __launch_bounds__(256) void gemm_in_k(const float* __restrict__ x,
                                                 const float* __restrict__ W,
                                                 float* __restrict__ xz) {
    __shared__ float As[16][128];
    __shared__ float Bs[16][128];
    const int b  = blockIdx.z;
    const int m0 = blockIdx.y * 128;
    const int n0 = blockIdx.x * 128;
    const int t  = threadIdx.x;
    const int tx = t & 15, ty = t >> 4;

    float acc[8][8];
#pragma unroll
    for (int i = 0; i < 8; ++i)
#pragma unroll
        for (int j = 0; j < 8; ++j) acc[i][j] = 0.f;

    for (int k0 = 0; k0 < DM; k0 += 16) {
#pragma unroll
        for (int i = 0; i < 2; ++i) {
            int slot = t + i * 256;
            int kc = slot >> 5;
            int p4 = (slot & 31) << 2;
            *(float4*)(&As[kc][p4]) =
                *(const float4*)(x + ((size_t)b * DM + k0 + kc) * LSEQ + m0 + p4);
            *(float4*)(&Bs[kc][p4]) =
                *(const float4*)(W + (size_t)(k0 + kc) * NIN + n0 + p4);
        }
        __syncthreads();
#pragma unroll
        for (int k = 0; k < 16; ++k) {
            float a[8], bb[8];
            *(float4*)(a)      = *(float4*)(&As[k][ty * 4]);
            *(float4*)(a + 4)  = *(float4*)(&As[k][64 + ty * 4]);
            *(float4*)(bb)     = *(float4*)(&Bs[k][tx * 4]);
            *(float4*)(bb + 4) = *(float4*)(&Bs[k][64 + tx * 4]);
#pragma unroll
            for (int i = 0; i < 8; ++i)
#pragma unroll
                for (int j = 0; j < 8; ++j) acc[i][j] = fmaf(a[i], bb[j], acc[i][j]);
        }
        __syncthreads();
    }
#pragma unroll
    for (int i = 0; i < 8; ++i) {
        int m = m0 + ((i < 4) ? (ty * 4 + i) : (64 + ty * 4 + i - 4));
        float* orow = xz + ((size_t)b * LSEQ + m) * NIN + n0;
        *(float4*)(orow + tx * 4)      = make_float4(acc[i][0], acc[i][1], acc[i][2], acc[i][3]);
        *(float4*)(orow + 64 + tx * 4) = make_float4(acc[i][4], acc[i][5], acc[i][6], acc[i][7]);
    }
}

// ---------------- conv + silu: xc[b,l,d] ----------------
__global__ __launch_bounds__(256) void conv_silu_k(const float* __restrict__ xz,
                                                   const float* __restrict__ conv_w,
                                                   const float* __restrict__ conv_b,
                                                   float* __restrict__ xc) {
    const int m = blockIdx.x;          // b*LSEQ + l
    const int d = threadIdx.x;
    const int b = m >> 12;
    const int l = m & (LSEQ - 1);
    float acc = conv_b[d];
#pragma unroll
    for (int k = 0; k < 4; ++k) {
        int ls = l - 3 + k;
        if (ls >= 0)
            acc = fmaf(xz[((size_t)b * LSEQ + ls) * NIN + d], conv_w[d * 4 + k], acc);
    }
    xc[(size_t)m * DI + d] = acc * sigmoid_f(acc);
}

// ---------------- gemm_x: dbc[m, 0:48] = xc[m,:] @ W_x ----------------
__global__ __launch_bounds__(256) void gemm_x_k(const float* __restrict__ xc,
                                                const float* __restrict__ Wx,
                                                float* __restrict__ dbc) {
    __shared__ float As[64][33];
    __shared__ float Ws[32][48];
    const int t  = threadIdx.x;
    const int m0 = blockIdx.x * 64;
    const int ml = t >> 2;
    const int n0 = (t & 3) * 12;
    float acc[12];
#pragma unroll
    for (int j = 0; j < 12; ++j) acc[j] = 0.f;

    for (int k0 = 0; k0 < DI; k0 += 32) {
#pragma unroll
        for (int i = 0; i < 8; ++i) {
            int idx = t + i * 256;
            int r = idx >> 5, kk = idx & 31;
            As[r][kk] = xc[(size_t)(m0 + r) * DI + k0 + kk];
        }
#pragma unroll
        for (int i = 0; i < 6; ++i) {
            int idx = t + i * 256;
            int r = idx / 48, kn = idx % 48;
            Ws[r][kn] = Wx[(size_t)(k0 + r) * NDBC + kn];
        }
        __syncthreads();
#pragma unroll
        for (int kk = 0; kk < 32; ++kk) {
            float a = As[ml][kk];
#pragma unroll
            for (int j = 0; j < 12; ++j) acc[j] = fmaf(a, Ws[kk][n0 + j], acc[j]);
        }
        __syncthreads();
    }
    float* orow = dbc + (size_t)(m0 + ml) * NDBC + n0;
#pragma unroll
    for (int j = 0; j < 12; ++j) orow[j] = acc[j];
}

// ---------------- gemm_dt + softplus: dt[m,d] ----------------
__global__ __launch_bounds__(256) void gemm_dt_k(const float* __restrict__ dbc,
                                                 const float* __restrict__ W_dt,
                                                 const float* __restrict__ b_dt,
                                                 float* __restrict__ dt) {
    const int m = blockIdx.x;
    const int d = threadIdx.x;
    const float* row = dbc + (size_t)m * NDBC;
    float acc = b_dt[d];
#pragma unroll
    for (int r = 0; r < DR; ++r) acc = fmaf(row[r], W_dt[r * DI + d], acc);
    float sp = fmaxf(acc, 0.f) + log1pf(expf(-fabsf(acc)));
    dt[(size_t)m * DI + d] = sp;
}

// ---------------- scan phase A: per-chunk decay product P and local final F ----------------
__global__ __launch_bounds__(256) void scan_a_k(const float* __restrict__ dt,
                                                const float* __restrict__ xc,
                                                const float* __restrict__ dbc,
                                                const float* __restrict__ A_log,
                                                float* __restrict__ Pst,
                                                float* __restrict__ Fst) {
    const int t = blockIdx.x * 256 + threadIdx.x;
    const int s     = t & 15;
    const int chunk = (t >> 4) & (NCHUNK - 1);
    const int d     = (t >> 10) & (DI - 1);
    const int b     = t >> 18;
    const float Ads = -expf(A_log[d * DS + s]);
    const int l0 = chunk * LCHUNK;
    const float* dtp = dt  + ((size_t)b * LSEQ + l0) * DI + d;
    const float* xcp = xc  + ((size_t)b * LSEQ + l0) * DI + d;
    const float* bmp = dbc + ((size_t)b * LSEQ + l0) * NDBC + DR + s;
    float h = 0.f, P = 1.f;
#pragma unroll 8
    for (int i = 0; i < LCHUNK; ++i) {
        float dtv = dtp[(size_t)i * DI];
        float a = expf(dtv * Ads);
        float u = dtv * xcp[(size_t)i * DI] * bmp[(size_t)i * NDBC];
        h = fmaf(h, a, u);
        P *= a;
    }
    const int cidx = (((b * DI + d) * NCHUNK) + chunk) * DS + s;
    Pst[cidx] = P;
    Fst[cidx] = h;
}

// ---------------- scan phase B: sequential over chunk boundaries ----------------
__global__ __launch_bounds__(256) void scan_b_k(const float* __restrict__ Pst,
                                                const float* __restrict__ Fst,
                                                float* __restrict__ carry) {
    const int t = blockIdx.x * 256 + threadIdx.x;   // 8192 threads
    const int s = t & 15;
    const int d = (t >> 4) & (DI - 1);
    const int b = t >> 12;
    size_t base = ((size_t)(b * DI + d) * NCHUNK) * DS + s;
    float st = 0.f;
#pragma unroll 8
    for (int c = 0; c < NCHUNK; ++c) {
        size_t idx = base + (size_t)c * DS;
        carry[idx] = st;
        st = fmaf(Pst[idx], st, Fst[idx]);
    }
}

// ---------------- scan phase C: full scan with carry, produce ypre (B,DI,L) ----------------
__global__ __launch_bounds__(256) void scan_c_k(const float* __restrict__ dt,
                                                const float* __restrict__ xc,
                                                const float* __restrict__ dbc,
                                                const float* __restrict__ xz,
                                                const float* __restrict__ A_log,
                                                const float* __restrict__ Dw,
                                                const float* __restrict__ carry,
                                                float* __restrict__ ypre) {
    const int t = blockIdx.x * 256 + threadIdx.x;
    const int s     = t & 15;
    const int chunk = (t >> 4) & (NCHUNK - 1);
    const int d     = (t >> 10) & (DI - 1);
    const int b     = t >> 18;
    const float Ads = -expf(A_log[d * DS + s]);
    const float Dd  = Dw[d];
    const int l0 = chunk * LCHUNK;
    const float* dtp  = dt  + ((size_t)b * LSEQ + l0) * DI + d;
    const float* xcp  = xc  + ((size_t)b * LSEQ + l0) * DI + d;
    const float* rowp = dbc + ((size_t)b * LSEQ + l0) * NDBC;
    const float* zp   = xz  + ((size_t)b * LSEQ + l0) * NIN + DI + d;
    const int cidx = (((b * DI + d) * NCHUNK) + chunk) * DS + s;
    float h = carry[cidx];
    float* yout = ypre + ((size_t)b * DI + d) * LSEQ + l0;

    for (int q = 0; q < LCHUNK / 16; ++q) {
        float ykeep = 0.f, xckeep = 0.f, zkeep = 0.f;
#pragma unroll
        for (int i = 0; i < 16; ++i) {
            int l = q * 16 + i;
            float dtv = dtp[(size_t)l * DI];
            float xcv = xcp[(size_t)l * DI];
            float zv  = zp[(size_t)l * NIN];
            float a = expf(dtv * Ads);
            float u = dtv * xcv * rowp[(size_t)l * NDBC + DR + s];
            h = fmaf(h, a, u);
            float yp = h * rowp[(size_t)l * NDBC + DR + DS + s];
            yp += __shfl_xor(yp, 1, 16);
            yp += __shfl_xor(yp, 2, 16);
            yp += __shfl_xor(yp, 4, 16);
            yp += __shfl_xor(yp, 8, 16);
            if (i == s) { ykeep = yp; xckeep = xcv; zkeep = zv; }
        }
        // lanes 0..15 hold l = l0 + q*16 + s  -> coalesced 64B store per group
        float yf = fmaf(xckeep, Dd, ykeep);
        yout[q * 16 + s] = yf * (zkeep * sigmoid_f(zkeep));
    }
}

// ---------------- gemm_out: out[b,c,l] = sum_d ypre[b,d,l] * W_out[d,c] ----------------
__global__ __launch_bounds__(256) void gemm_out_k(const float* __restrict__ ypre,
                                                  const float* __restrict__ W,
                                                  float* __restrict__ out) {
    __shared__ float As[16][128];
    __shared__ float Bs[16][128];
    const int b  = blockIdx.z;
    const int m0 = blockIdx.y * 128;   // l
    const int n0 = blockIdx.x * 128;   // c
    const int t  = threadIdx.x;
    const int tx = t & 15, ty = t >> 4;

    float acc[8][8];
#pragma unroll
    for (int i = 0; i < 8; ++i)
#pragma unroll
        for (int j = 0; j < 8; ++j) acc[i][j] = 0.f;

    for (int k0 = 0; k0 < DI; k0 += 16) {
#pragma unroll
        for (int i = 0; i < 2; ++i) {
            int slot = t + i * 256;
            int kc = slot >> 5;
            int p4 = (slot & 31) << 2;
            *(float4*)(&As[kc][p4]) =
                *(const float4*)(ypre + ((size_t)b * DI + k0 + kc) * LSEQ + m0 + p4);
            *(float4*)(&Bs[kc][p4]) =
                *(const float4*)(W + (size_t)(k0 + kc) * DM + n0 + p4);
        }
        __syncthreads();
#pragma unroll
        for (int k = 0; k < 16; ++k) {
            float a[8], bb[8];
            *(float4*)(a)      = *(float4*)(&As[k][ty * 4]);
            *(float4*)(a + 4)  = *(float4*)(&As[k][64 + ty * 4]);
            *(float4*)(bb)     = *(float4*)(&Bs[k][tx * 4]);
            *(float4*)(bb + 4) = *(float4*)(&Bs[k][64 + tx * 4]);
#pragma unroll
            for (int i = 0; i < 8; ++i)
#pragma unroll
                for (int j = 0; j < 8; ++j) acc[i][j] = fmaf(a[i], bb[j], acc[i][j]);
        }
        __syncthreads();
    }
    // out[(b*DM + c)*LSEQ + l]; rows (i) are l, cols (j) are c
#pragma unroll
    for (int j = 0; j < 8; ++j) {
        int c = n0 + ((j < 4) ? (tx * 4 + j) : (64 + tx * 4 + j - 4));
        float* ocol = out + ((size_t)b * DM + c) * LSEQ + m0;
        *(float4*)(ocol + ty * 4)      = make_float4(acc[0][j], acc[1][j], acc[2][j], acc[3][j]);
        *(float4*)(ocol + 64 + ty * 4) = make_float4(acc[4][j], acc[5][j], acc[6][j], acc[7][j]);
    }
}

extern "C" void kernel_launch(void* const* d_in, const int* in_sizes, int n_in,
                              void* d_out, int out_size, void* d_ws, size_t ws_size,
                              hipStream_t stream) {
    const float* x      = (const float*)d_in[0];
    const float* W_in   = (const float*)d_in[1];
    const float* conv_w = (const float*)d_in[2];
    const float* conv_b = (const float*)d_in[3];
    const float* W_x    = (const float*)d_in[4];
    const float* W_dt   = (const float*)d_in[5];
    const float* b_dt   = (const float*)d_in[6];
    const float* A_log  = (const float*)d_in[7];
    const float* Dw     = (const float*)d_in[8];
    const float* W_out  = (const float*)d_in[9];
    float* out = (float*)d_out;

    float* ws    = (float*)d_ws;
    float* xz    = ws;                    // B*L*512  = 4,194,304
    float* xc    = xz + 4194304;          // B*L*256  = 2,097,152
    float* dbc   = xc + 2097152;          // B*L*48   =   393,216
    float* dtb   = dbc + 393216;          // B*L*256  = 2,097,152
    float* Pst   = dtb + 2097152;         // B*D*NC*S =   524,288
    float* Fst   = Pst + 524288;
    float* carry = Fst + 524288;
    float* ypre  = carry + 524288;        // B*D*L    = 2,097,152

    gemm_in_k <<<dim3(4, 32, BSZ), 256, 0, stream>>>(x, W_in, xz);
    conv_silu_k<<<dim3(BSZ * LSEQ), 256, 0, stream>>>(xz, conv_w, conv_b, xc);
    gemm_x_k  <<<dim3(BSZ * LSEQ / 64), 256, 0, stream>>>(xc, W_x, dbc);
    gemm_dt_k <<<dim3(BSZ * LSEQ), 256, 0, stream>>>(dbc, W_dt, b_dt, dtb);
    scan_a_k  <<<dim3(BSZ * DI * NCHUNK * DS / 256), 256, 0, stream>>>(dtb, xc, dbc, A_log, Pst, Fst);
    scan_b_k  <<<dim3(BSZ * DI * DS / 256), 256, 0, stream>>>(Pst, Fst, carry);
    scan_c_k  <<<dim3(BSZ * DI * NCHUNK * DS / 256), 256, 0, stream>>>(dtb, xc, dbc, xz, A_log, Dw, carry, ypre);
    gemm_out_k<<<dim3(2, 32, BSZ), 256, 0, stream>>>(ypre, W_out, out);
}

// Round 2
// 244.537 us; speedup vs baseline: 1.2069x; 1.2069x over previous
//
#include <hip/hip_runtime.h>
#include <math.h>

#define BSZ 2
#define LSEQ 4096
#define DM 256      // d_model
#define DI 256      // d_inner
#define DS 16       // d_state
#define DR 16       // dt_rank
#define NIN 512     // 2*DI
#define NDBC 48     // DR + 2*DS
#define NCHUNK 128
#define LCHUNK 32

__device__ __forceinline__ float sigmoid_f(float v) {
    return __builtin_amdgcn_rcpf(1.0f + __expf(-v));
}

// ---------------- gemm_in: xz[b,l,n] = sum_c x[b,c,l] * W_in[c,n] ----------------
__global__ __launch_bounds__(256) void gemm_in_k(const float* __restrict__ x,
                                                 const float* __restrict__ W,
                                                 float* __restrict__ xz) {
    __shared__ float As[16][128];
    __shared__ float Bs[16][128];
    const int b  = blockIdx.z;
    const int m0 = blockIdx.y * 128;
    const int n0 = blockIdx.x * 128;
    const int t  = threadIdx.x;
    const int tx = t & 15, ty = t >> 4;

    float acc[8][8];
#pragma unroll
    for (int i = 0; i < 8; ++i)
#pragma unroll
        for (int j = 0; j < 8; ++j) acc[i][j] = 0.f;

    for (int k0 = 0; k0 < DM; k0 += 16) {
#pragma unroll
        for (int i = 0; i < 2; ++i) {
            int slot = t + i * 256;
            int kc = slot >> 5;
            int p4 = (slot & 31) << 2;
            *(float4*)(&As[kc][p4]) =
                *(const float4*)(x + ((size_t)b * DM + k0 + kc) * LSEQ + m0 + p4);
            *(float4*)(&Bs[kc][p4]) =
                *(const float4*)(W + (size_t)(k0 + kc) * NIN + n0 + p4);
        }
        __syncthreads();
#pragma unroll
        for (int k = 0; k < 16; ++k) {
            float a[8], bb[8];
            *(float4*)(a)      = *(float4*)(&As[k][ty * 4]);
            *(float4*)(a + 4)  = *(float4*)(&As[k][64 + ty * 4]);
            *(float4*)(bb)     = *(float4*)(&Bs[k][tx * 4]);
            *(float4*)(bb + 4) = *(float4*)(&Bs[k][64 + tx * 4]);
#pragma unroll
            for (int i = 0; i < 8; ++i)
#pragma unroll
                for (int j = 0; j < 8; ++j) acc[i][j] = fmaf(a[i], bb[j], acc[i][j]);
        }
        __syncthreads();
    }
#pragma unroll
    for (int i = 0; i < 8; ++i) {
        int m = m0 + ((i < 4) ? (ty * 4 + i) : (64 + ty * 4 + i - 4));
        float* orow = xz + ((size_t)b * LSEQ + m) * NIN + n0;
        *(float4*)(orow + tx * 4)      = make_float4(acc[i][0], acc[i][1], acc[i][2], acc[i][3]);
        *(float4*)(orow + 64 + tx * 4) = make_float4(acc[i][4], acc[i][5], acc[i][6], acc[i][7]);
    }
}

// ---------------- conv + silu: xc[b,l,d] ----------------
__global__ __launch_bounds__(256) void conv_silu_k(const float* __restrict__ xz,
                                                   const float* __restrict__ conv_w,
                                                   const float* __restrict__ conv_b,
                                                   float* __restrict__ xc) {
    const int m = blockIdx.x;          // b*LSEQ + l
    const int d = threadIdx.x;
    const int b = m >> 12;
    const int l = m & (LSEQ - 1);
    float acc = conv_b[d];
#pragma unroll
    for (int k = 0; k < 4; ++k) {
        int ls = l - 3 + k;
        if (ls >= 0)
            acc = fmaf(xz[((size_t)b * LSEQ + ls) * NIN + d], conv_w[d * 4 + k], acc);
    }
    xc[(size_t)m * DI + d] = acc * sigmoid_f(acc);
}

// ---------------- gemm_x: dbc[m, 0:48] = xc[m,:] @ W_x ----------------
__global__ __launch_bounds__(256) void gemm_x_k(const float* __restrict__ xc,
                                                const float* __restrict__ Wx,
                                                float* __restrict__ dbc) {
    __shared__ float As[64][33];
    __shared__ float Ws[32][48];
    const int t  = threadIdx.x;
    const int m0 = blockIdx.x * 64;
    const int ml = t >> 2;
    const int n0 = (t & 3) * 12;
    float acc[12];
#pragma unroll
    for (int j = 0; j < 12; ++j) acc[j] = 0.f;

    for (int k0 = 0; k0 < DI; k0 += 32) {
#pragma unroll
        for (int i = 0; i < 8; ++i) {
            int idx = t + i * 256;
            int r = idx >> 5, kk = idx & 31;
            As[r][kk] = xc[(size_t)(m0 + r) * DI + k0 + kk];
        }
#pragma unroll
        for (int i = 0; i < 6; ++i) {
            int idx = t + i * 256;
            int r = idx / 48, kn = idx % 48;
            Ws[r][kn] = Wx[(size_t)(k0 + r) * NDBC + kn];
        }
        __syncthreads();
#pragma unroll
        for (int kk = 0; kk < 32; ++kk) {
            float a = As[ml][kk];
#pragma unroll
            for (int j = 0; j < 12; ++j) acc[j] = fmaf(a, Ws[kk][n0 + j], acc[j]);
        }
        __syncthreads();
    }
    float* orow = dbc + (size_t)(m0 + ml) * NDBC + n0;
#pragma unroll
    for (int j = 0; j < 12; ++j) orow[j] = acc[j];
}

// ---------------- gemm_dt + softplus: dt[m,d] ----------------
__global__ __launch_bounds__(256) void gemm_dt_k(const float* __restrict__ dbc,
                                                 const float* __restrict__ W_dt,
                                                 const float* __restrict__ b_dt,
                                                 float* __restrict__ dt) {
    const int m = blockIdx.x;
    const int d = threadIdx.x;
    const float* row = dbc + (size_t)m * NDBC;
    float acc = b_dt[d];
#pragma unroll
    for (int r = 0; r < DR; ++r) acc = fmaf(row[r], W_dt[r * DI + d], acc);
    float sp = fmaxf(acc, 0.f) + log1pf(expf(-fabsf(acc)));
    dt[(size_t)m * DI + d] = sp;
}

// ---------------- scan phase A: per-chunk decay product P and local final F ----------------
// One thread per (b, d, chunk); h[16], P[16] in registers. Block = 256 d's, one chunk.
__global__ __launch_bounds__(256) void scan_a_k(const float* __restrict__ dt,
                                                const float* __restrict__ xc,
                                                const float* __restrict__ dbc,
                                                const float* __restrict__ A_log,
                                                float* __restrict__ Pst,
                                                float* __restrict__ Fst) {
    __shared__ float Bl[LCHUNK][16];
    const int blk   = blockIdx.x;
    const int b     = blk >> 7;            // NCHUNK = 128
    const int chunk = blk & (NCHUNK - 1);
    const int d     = threadIdx.x;
    const int l0    = chunk * LCHUNK;

    if (d < LCHUNK * 4) {
        int l = d >> 2, q = d & 3;
        *(float4*)(&Bl[l][q * 4]) =
            *(const float4*)(dbc + (size_t)(b * LSEQ + l0 + l) * NDBC + DR + q * 4);
    }
    float Ads[16];
#pragma unroll
    for (int s = 0; s < 16; ++s) Ads[s] = -expf(A_log[d * DS + s]);
    __syncthreads();

    float h[16], P[16];
#pragma unroll
    for (int s = 0; s < 16; ++s) { h[s] = 0.f; P[s] = 1.f; }

    const float* dtp = dt + ((size_t)b * LSEQ + l0) * DI + d;
    const float* xcp = xc + ((size_t)b * LSEQ + l0) * DI + d;

#pragma unroll 4
    for (int i = 0; i < LCHUNK; ++i) {
        float dtv = dtp[(size_t)i * DI];
        float xcv = xcp[(size_t)i * DI];
        float du  = dtv * xcv;
        float4 b0 = *(float4*)(&Bl[i][0]);
        float4 b1 = *(float4*)(&Bl[i][4]);
        float4 b2 = *(float4*)(&Bl[i][8]);
        float4 b3 = *(float4*)(&Bl[i][12]);
        float bv[16] = {b0.x,b0.y,b0.z,b0.w, b1.x,b1.y,b1.z,b1.w,
                        b2.x,b2.y,b2.z,b2.w, b3.x,b3.y,b3.z,b3.w};
#pragma unroll
        for (int s = 0; s < 16; ++s) {
            float a = __expf(dtv * Ads[s]);
            h[s] = fmaf(h[s], a, du * bv[s]);
            P[s] *= a;
        }
    }
    size_t base = ((size_t)(b * DI + d) * NCHUNK + chunk) * DS;
#pragma unroll
    for (int q = 0; q < 4; ++q) {
        *(float4*)(Pst + base + q * 4) = make_float4(P[q*4], P[q*4+1], P[q*4+2], P[q*4+3]);
        *(float4*)(Fst + base + q * 4) = make_float4(h[q*4], h[q*4+1], h[q*4+2], h[q*4+3]);
    }
}

// ---------------- scan phase B: sequential over chunk boundaries, in-place carry into Fst ----------------
__global__ __launch_bounds__(256) void scan_b_k(const float* __restrict__ Pst,
                                                float* __restrict__ Fst) {
    const int t = blockIdx.x * 256 + threadIdx.x;   // 8192 threads: (b,d,s)
    const int s = t & 15;
    const int d = (t >> 4) & (DI - 1);
    const int b = t >> 12;
    size_t base = ((size_t)(b * DI + d) * NCHUNK) * DS + s;
    float st = 0.f;
#pragma unroll 8
    for (int c = 0; c < NCHUNK; ++c) {
        size_t idx = base + (size_t)c * DS;
        float P = Pst[idx];
        float F = Fst[idx];
        Fst[idx] = st;                 // carry-in for chunk c
        st = fmaf(P, st, F);
    }
}

// ---------------- scan phase C: full scan with carry, produce y (B,L,DI) ----------------
__global__ __launch_bounds__(256) void scan_c_k(const float* __restrict__ dt,
                                                const float* __restrict__ xc,
                                                const float* __restrict__ dbc,
                                                const float* __restrict__ xz,
                                                const float* __restrict__ A_log,
                                                const float* __restrict__ Dw,
                                                const float* __restrict__ carry,
                                                float* __restrict__ y) {
    __shared__ float BC[LCHUNK][32];   // [:,0:16]=B row, [:,16:32]=C row
    const int blk   = blockIdx.x;
    const int b     = blk >> 7;
    const int chunk = blk & (NCHUNK - 1);
    const int d     = threadIdx.x;
    const int l0    = chunk * LCHUNK;

    {
        int l = d >> 3, q = d & 7;     // 256 threads = 32 l * 8 float4
        *(float4*)(&BC[l][q * 4]) =
            *(const float4*)(dbc + (size_t)(b * LSEQ + l0 + l) * NDBC + DR + q * 4);
    }
    float Ads[16];
#pragma unroll
    for (int s = 0; s < 16; ++s) Ads[s] = -expf(A_log[d * DS + s]);
    const float Dd = Dw[d];

    float h[16];
    size_t cbase = ((size_t)(b * DI + d) * NCHUNK + chunk) * DS;
#pragma unroll
    for (int q = 0; q < 4; ++q) {
        float4 c4 = *(const float4*)(carry + cbase + q * 4);
        h[q*4] = c4.x; h[q*4+1] = c4.y; h[q*4+2] = c4.z; h[q*4+3] = c4.w;
    }
    __syncthreads();

    const float* dtp = dt + ((size_t)b * LSEQ + l0) * DI + d;
    const float* xcp = xc + ((size_t)b * LSEQ + l0) * DI + d;
    const float* zp  = xz + ((size_t)b * LSEQ + l0) * NIN + DI + d;
    float* yout      = y  + ((size_t)b * LSEQ + l0) * DI + d;

#pragma unroll 4
    for (int i = 0; i < LCHUNK; ++i) {
        float dtv = dtp[(size_t)i * DI];
        float xcv = xcp[(size_t)i * DI];
        float zv  = zp[(size_t)i * NIN];
        float du  = dtv * xcv;
        float4 b0 = *(float4*)(&BC[i][0]);
        float4 b1 = *(float4*)(&BC[i][4]);
        float4 b2 = *(float4*)(&BC[i][8]);
        float4 b3 = *(float4*)(&BC[i][12]);
        float4 c0 = *(float4*)(&BC[i][16]);
        float4 c1 = *(float4*)(&BC[i][20]);
        float4 c2 = *(float4*)(&BC[i][24]);
        float4 c3 = *(float4*)(&BC[i][28]);
        float bv[16] = {b0.x,b0.y,b0.z,b0.w, b1.x,b1.y,b1.z,b1.w,
                        b2.x,b2.y,b2.z,b2.w, b3.x,b3.y,b3.z,b3.w};
        float cv[16] = {c0.x,c0.y,c0.z,c0.w, c1.x,c1.y,c1.z,c1.w,
                        c2.x,c2.y,c2.z,c2.w, c3.x,c3.y,c3.z,c3.w};
        float yv = 0.f;
#pragma unroll
        for (int s = 0; s < 16; ++s) {
            float a = __expf(dtv * Ads[s]);
            h[s] = fmaf(h[s], a, du * bv[s]);
            yv = fmaf(h[s], cv[s], yv);
        }
        float yf = fmaf(xcv, Dd, yv);
        yout[(size_t)i * DI] = yf * (zv * sigmoid_f(zv));
    }
}

// ---------------- gemm_out: out[b,c,l] = sum_d y[b,l,d] * W_out[d,c] ----------------
// A = y in (B,L,DI): k-contiguous rows, transposed into LDS tile.
__global__ __launch_bounds__(256) void gemm_out_k(const float* __restrict__ y,
                                                  const float* __restrict__ W,
                                                  float* __restrict__ out) {
    __shared__ float As[16][132];
    __shared__ float Bs[16][128];
    const int b  = blockIdx.z;
    const int m0 = blockIdx.y * 128;   // l
    const int n0 = blockIdx.x * 128;   // c
    const int t  = threadIdx.x;
    const int tx = t & 15, ty = t >> 4;

    float acc[8][8];
#pragma unroll
    for (int i = 0; i < 8; ++i)
#pragma unroll
        for (int j = 0; j < 8; ++j) acc[i][j] = 0.f;

    for (int k0 = 0; k0 < DI; k0 += 16) {
#pragma unroll
        for (int i = 0; i < 2; ++i) {
            int slot = t + i * 256;
            // A tile: 128 m-rows, 16 k each, transpose into As[k][m]
            int m = slot >> 2, q = slot & 3;
            float4 v = *(const float4*)(y + ((size_t)b * LSEQ + m0 + m) * DI + k0 + q * 4);
            As[q * 4 + 0][m] = v.x;
            As[q * 4 + 1][m] = v.y;
            As[q * 4 + 2][m] = v.z;
            As[q * 4 + 3][m] = v.w;
            // B tile
            int kc = slot >> 5;
            int p4 = (slot & 31) << 2;
            *(float4*)(&Bs[kc][p4]) =
                *(const float4*)(W + (size_t)(k0 + kc) * DM + n0 + p4);
        }
        __syncthreads();
#pragma unroll
        for (int k = 0; k < 16; ++k) {
            float a[8], bb[8];
            *(float4*)(a)      = *(float4*)(&As[k][ty * 4]);
            *(float4*)(a + 4)  = *(float4*)(&As[k][64 + ty * 4]);
            *(float4*)(bb)     = *(float4*)(&Bs[k][tx * 4]);
            *(float4*)(bb + 4) = *(float4*)(&Bs[k][64 + tx * 4]);
#pragma unroll
            for (int i = 0; i < 8; ++i)
#pragma unroll
                for (int j = 0; j < 8; ++j) acc[i][j] = fmaf(a[i], bb[j], acc[i][j]);
        }
        __syncthreads();
    }
#pragma unroll
    for (int j = 0; j < 8; ++j) {
        int c = n0 + ((j < 4) ? (tx * 4 + j) : (64 + tx * 4 + j - 4));
        float* ocol = out + ((size_t)b * DM + c) * LSEQ + m0;
        *(float4*)(ocol + ty * 4)      = make_float4(acc[0][j], acc[1][j], acc[2][j], acc[3][j]);
        *(float4*)(ocol + 64 + ty * 4) = make_float4(acc[4][j], acc[5][j], acc[6][j], acc[7][j]);
    }
}

extern "C" void kernel_launch(void* const* d_in, const int* in_sizes, int n_in,
                              void* d_out, int out_size, void* d_ws, size_t ws_size,
                              hipStream_t stream) {
    const float* x      = (const float*)d_in[0];
    const float* W_in   = (const float*)d_in[1];
    const float* conv_w = (const float*)d_in[2];
    const float* conv_b = (const float*)d_in[3];
    const float* W_x    = (const float*)d_in[4];
    const float* W_dt   = (const float*)d_in[5];
    const float* b_dt   = (const float*)d_in[6];
    const float* A_log  = (const float*)d_in[7];
    const float* Dw     = (const float*)d_in[8];
    const float* W_out  = (const float*)d_in[9];
    float* out = (float*)d_out;

    float* ws   = (float*)d_ws;
    float* xz   = ws;                    // B*L*512            = 4,194,304
    float* xc   = xz + 4194304;          // B*L*256            = 2,097,152
    float* dbc  = xc + 2097152;          // B*L*48             =   393,216
    float* dtb  = dbc + 393216;          // B*L*256            = 2,097,152
    float* Pst  = dtb + 2097152;         // B*DI*NCHUNK*DS     = 1,048,576
    float* Fst  = Pst + 1048576;         // 1,048,576 (carry written in-place)
    float* yb   = Fst + 1048576;         // B*L*DI             = 2,097,152

    gemm_in_k  <<<dim3(4, 32, BSZ), 256, 0, stream>>>(x, W_in, xz);
    conv_silu_k<<<dim3(BSZ * LSEQ), 256, 0, stream>>>(xz, conv_w, conv_b, xc);
    gemm_x_k   <<<dim3(BSZ * LSEQ / 64), 256, 0, stream>>>(xc, W_x, dbc);
    gemm_dt_k  <<<dim3(BSZ * LSEQ), 256, 0, stream>>>(dbc, W_dt, b_dt, dtb);
    scan_a_k   <<<dim3(BSZ * NCHUNK), 256, 0, stream>>>(dtb, xc, dbc, A_log, Pst, Fst);
    scan_b_k   <<<dim3(BSZ * DI * DS / 256), 256, 0, stream>>>(Pst, Fst);
    scan_c_k   <<<dim3(BSZ * NCHUNK), 256, 0, stream>>>(dtb, xc, dbc, xz, A_log, Dw, Fst, yb);
    gemm_out_k <<<dim3(2, 32, BSZ), 256, 0, stream>>>(yb, W_out, out);
}

// Round 3
// 224.709 us; speedup vs baseline: 1.3133x; 1.0882x over previous
//
#include <hip/hip_runtime.h>
#include <math.h>

#define BSZ 2
#define LSEQ 4096
#define DM 256      // d_model
#define DI 256      // d_inner
#define DS 16       // d_state
#define DR 16       // dt_rank
#define NIN 512     // 2*DI
#define NCHUNK 128
#define LCHUNK 32

__device__ __forceinline__ float sigmoid_f(float v) {
    return __builtin_amdgcn_rcpf(1.0f + __expf(-v));
}

// ---------------- gemm_in: xz[b,l,n] = sum_c x[b,c,l] * W_in[c,n] ----------------
// 64x64 tile, 4x4 micro-tile, 1024 blocks -> 4 blocks/CU.
__global__ __launch_bounds__(256) void gemm_in_k(const float* __restrict__ x,
                                                 const float* __restrict__ W,
                                                 float* __restrict__ xz) {
    __shared__ float As[32][64];
    __shared__ float Bs[32][64];
    const int b  = blockIdx.z;
    const int m0 = blockIdx.y * 64;
    const int n0 = blockIdx.x * 64;
    const int t  = threadIdx.x;
    const int tx = t & 15, ty = t >> 4;

    float acc[4][4];
#pragma unroll
    for (int i = 0; i < 4; ++i)
#pragma unroll
        for (int j = 0; j < 4; ++j) acc[i][j] = 0.f;

    for (int k0 = 0; k0 < DM; k0 += 32) {
#pragma unroll
        for (int i = 0; i < 2; ++i) {
            int slot = t + i * 256;
            int kc = slot >> 4;            // 0..31
            int p4 = (slot & 15) << 2;     // 0..60
            *(float4*)(&As[kc][p4]) =
                *(const float4*)(x + ((size_t)b * DM + k0 + kc) * LSEQ + m0 + p4);
            *(float4*)(&Bs[kc][p4]) =
                *(const float4*)(W + (size_t)(k0 + kc) * NIN + n0 + p4);
        }
        __syncthreads();
#pragma unroll
        for (int k = 0; k < 32; ++k) {
            float a[4], bb[4];
            *(float4*)(a)  = *(float4*)(&As[k][ty * 4]);
            *(float4*)(bb) = *(float4*)(&Bs[k][tx * 4]);
#pragma unroll
            for (int i = 0; i < 4; ++i)
#pragma unroll
                for (int j = 0; j < 4; ++j) acc[i][j] = fmaf(a[i], bb[j], acc[i][j]);
        }
        __syncthreads();
    }
#pragma unroll
    for (int i = 0; i < 4; ++i) {
        int m = m0 + ty * 4 + i;
        float* orow = xz + ((size_t)b * LSEQ + m) * NIN + n0;
        *(float4*)(orow + tx * 4) = make_float4(acc[i][0], acc[i][1], acc[i][2], acc[i][3]);
    }
}

// ---------------- fused conv+silu + gemm_x + gemm_dt ----------------
// One block per m = b*L + l. Outputs: xc (B,L,DI), bc (B,L,32) [B|C], dt (B,L,DI).
__global__ __launch_bounds__(256) void convx_k(const float* __restrict__ xz,
                                               const float* __restrict__ conv_w,
                                               const float* __restrict__ conv_b,
                                               const float* __restrict__ W_x,
                                               const float* __restrict__ W_dt,
                                               const float* __restrict__ b_dt,
                                               float* __restrict__ xc,
                                               float* __restrict__ bc,
                                               float* __restrict__ dt) {
    __shared__ float xcL[DI];
    __shared__ float part[48][4];
    __shared__ float dbcL[16];
    const int m = blockIdx.x;
    const int b = m >> 12;
    const int l = m & (LSEQ - 1);
    const int d = threadIdx.x;

    float acc = conv_b[d];
#pragma unroll
    for (int k = 0; k < 4; ++k) {
        int ls = l - 3 + k;
        if (ls >= 0)
            acc = fmaf(xz[((size_t)b * LSEQ + ls) * NIN + d], conv_w[d * 4 + k], acc);
    }
    float xcv = acc * sigmoid_f(acc);
    xc[(size_t)m * DI + d] = xcv;
    xcL[d] = xcv;
    __syncthreads();

    if (d < 192) {
        const int o   = d >> 2;        // 0..47
        const int seg = d & 3;         // k segment of 64
        const float* wp = W_x + (size_t)(seg * 64) * 48 + o;
        const float* xp = xcL + seg * 64;
        float s0 = 0.f, s1 = 0.f, s2 = 0.f, s3 = 0.f;
#pragma unroll 8
        for (int i = 0; i < 64; i += 4) {
            s0 = fmaf(xp[i + 0], wp[(i + 0) * 48], s0);
            s1 = fmaf(xp[i + 1], wp[(i + 1) * 48], s1);
            s2 = fmaf(xp[i + 2], wp[(i + 2) * 48], s2);
            s3 = fmaf(xp[i + 3], wp[(i + 3) * 48], s3);
        }
        part[o][seg] = (s0 + s1) + (s2 + s3);
    }
    __syncthreads();

    if (d < 48) {
        float4 p4 = *(float4*)(&part[d][0]);
        float v = (p4.x + p4.y) + (p4.z + p4.w);
        if (d < 16) dbcL[d] = v;
        else        bc[(size_t)m * 32 + (d - 16)] = v;
    }
    __syncthreads();

    float a2 = b_dt[d];
#pragma unroll
    for (int r = 0; r < DR; ++r) a2 = fmaf(dbcL[r], W_dt[r * DI + d], a2);
    float sp = fmaxf(a2, 0.f) + log1pf(expf(-fabsf(a2)));
    dt[(size_t)m * DI + d] = sp;
}

// ---------------- scan phase A: per-chunk decay product P and local final F ----------------
__global__ __launch_bounds__(256) void scan_a_k(const float* __restrict__ dt,
                                                const float* __restrict__ xc,
                                                const float* __restrict__ bc,
                                                const float* __restrict__ A_log,
                                                float* __restrict__ Pst,
                                                float* __restrict__ Fst) {
    __shared__ float Bl[LCHUNK][16];
    const int blk   = blockIdx.x;
    const int b     = blk >> 7;            // NCHUNK = 128
    const int chunk = blk & (NCHUNK - 1);
    const int d     = threadIdx.x;
    const int l0    = chunk * LCHUNK;

    if (d < LCHUNK * 4) {
        int l = d >> 2, q = d & 3;
        *(float4*)(&Bl[l][q * 4]) =
            *(const float4*)(bc + (size_t)(b * LSEQ + l0 + l) * 32 + q * 4);
    }
    float Ads[16];
#pragma unroll
    for (int s = 0; s < 16; ++s) Ads[s] = -expf(A_log[d * DS + s]);
    __syncthreads();

    float h[16], P[16];
#pragma unroll
    for (int s = 0; s < 16; ++s) { h[s] = 0.f; P[s] = 1.f; }

    const float* dtp = dt + ((size_t)b * LSEQ + l0) * DI + d;
    const float* xcp = xc + ((size_t)b * LSEQ + l0) * DI + d;

#pragma unroll 4
    for (int i = 0; i < LCHUNK; ++i) {
        float dtv = dtp[(size_t)i * DI];
        float xcv = xcp[(size_t)i * DI];
        float du  = dtv * xcv;
        float4 b0 = *(float4*)(&Bl[i][0]);
        float4 b1 = *(float4*)(&Bl[i][4]);
        float4 b2 = *(float4*)(&Bl[i][8]);
        float4 b3 = *(float4*)(&Bl[i][12]);
        float bv[16] = {b0.x,b0.y,b0.z,b0.w, b1.x,b1.y,b1.z,b1.w,
                        b2.x,b2.y,b2.z,b2.w, b3.x,b3.y,b3.z,b3.w};
#pragma unroll
        for (int s = 0; s < 16; ++s) {
            float a = __expf(dtv * Ads[s]);
            h[s] = fmaf(h[s], a, du * bv[s]);
            P[s] *= a;
        }
    }
    size_t base = ((size_t)(b * DI + d) * NCHUNK + chunk) * DS;
#pragma unroll
    for (int q = 0; q < 4; ++q) {
        *(float4*)(Pst + base + q * 4) = make_float4(P[q*4], P[q*4+1], P[q*4+2], P[q*4+3]);
        *(float4*)(Fst + base + q * 4) = make_float4(h[q*4], h[q*4+1], h[q*4+2], h[q*4+3]);
    }
}

// ---------------- scan phase B: sequential over chunk boundaries, carry in-place into Fst ----------------
__global__ __launch_bounds__(256) void scan_b_k(const float* __restrict__ Pst,
                                                float* __restrict__ Fst) {
    const int t = blockIdx.x * 256 + threadIdx.x;   // 8192 threads: (b,d,s)
    const int s = t & 15;
    const int d = (t >> 4) & (DI - 1);
    const int b = t >> 12;
    size_t base = ((size_t)(b * DI + d) * NCHUNK) * DS + s;
    float st = 0.f;
#pragma unroll 8
    for (int c = 0; c < NCHUNK; ++c) {
        size_t idx = base + (size_t)c * DS;
        float P = Pst[idx];
        float F = Fst[idx];
        Fst[idx] = st;                 // carry-in for chunk c
        st = fmaf(P, st, F);
    }
}

// ---------------- scan phase C: full scan with carry, produce y (B,L,DI) ----------------
__global__ __launch_bounds__(256) void scan_c_k(const float* __restrict__ dt,
                                                const float* __restrict__ xc,
                                                const float* __restrict__ bc,
                                                const float* __restrict__ xz,
                                                const float* __restrict__ A_log,
                                                const float* __restrict__ Dw,
                                                const float* __restrict__ carry,
                                                float* __restrict__ y) {
    __shared__ float BC[LCHUNK][32];   // [:,0:16]=B row, [:,16:32]=C row
    const int blk   = blockIdx.x;
    const int b     = blk >> 7;
    const int chunk = blk & (NCHUNK - 1);
    const int d     = threadIdx.x;
    const int l0    = chunk * LCHUNK;

    {
        int l = d >> 3, q = d & 7;     // 256 threads = 32 l * 8 float4
        *(float4*)(&BC[l][q * 4]) =
            *(const float4*)(bc + (size_t)(b * LSEQ + l0 + l) * 32 + q * 4);
    }
    float Ads[16];
#pragma unroll
    for (int s = 0; s < 16; ++s) Ads[s] = -expf(A_log[d * DS + s]);
    const float Dd = Dw[d];

    float h[16];
    size_t cbase = ((size_t)(b * DI + d) * NCHUNK + chunk) * DS;
#pragma unroll
    for (int q = 0; q < 4; ++q) {
        float4 c4 = *(const float4*)(carry + cbase + q * 4);
        h[q*4] = c4.x; h[q*4+1] = c4.y; h[q*4+2] = c4.z; h[q*4+3] = c4.w;
    }
    __syncthreads();

    const float* dtp = dt + ((size_t)b * LSEQ + l0) * DI + d;
    const float* xcp = xc + ((size_t)b * LSEQ + l0) * DI + d;
    const float* zp  = xz + ((size_t)b * LSEQ + l0) * NIN + DI + d;
    float* yout      = y  + ((size_t)b * LSEQ + l0) * DI + d;

#pragma unroll 4
    for (int i = 0; i < LCHUNK; ++i) {
        float dtv = dtp[(size_t)i * DI];
        float xcv = xcp[(size_t)i * DI];
        float zv  = zp[(size_t)i * NIN];
        float du  = dtv * xcv;
        float4 b0 = *(float4*)(&BC[i][0]);
        float4 b1 = *(float4*)(&BC[i][4]);
        float4 b2 = *(float4*)(&BC[i][8]);
        float4 b3 = *(float4*)(&BC[i][12]);
        float4 c0 = *(float4*)(&BC[i][16]);
        float4 c1 = *(float4*)(&BC[i][20]);
        float4 c2 = *(float4*)(&BC[i][24]);
        float4 c3 = *(float4*)(&BC[i][28]);
        float bv[16] = {b0.x,b0.y,b0.z,b0.w, b1.x,b1.y,b1.z,b1.w,
                        b2.x,b2.y,b2.z,b2.w, b3.x,b3.y,b3.z,b3.w};
        float cv[16] = {c0.x,c0.y,c0.z,c0.w, c1.x,c1.y,c1.z,c1.w,
                        c2.x,c2.y,c2.z,c2.w, c3.x,c3.y,c3.z,c3.w};
        float yv = 0.f;
#pragma unroll
        for (int s = 0; s < 16; ++s) {
            float a = __expf(dtv * Ads[s]);
            h[s] = fmaf(h[s], a, du * bv[s]);
            yv = fmaf(h[s], cv[s], yv);
        }
        float yf = fmaf(xcv, Dd, yv);
        yout[(size_t)i * DI] = yf * (zv * sigmoid_f(zv));
    }
}

// ---------------- gemm_out: out[b,c,l] = sum_d y[b,l,d] * W_out[d,c] ----------------
// 64x64 tile, A (y) transposed through LDS.
__global__ __launch_bounds__(256) void gemm_out_k(const float* __restrict__ y,
                                                  const float* __restrict__ W,
                                                  float* __restrict__ out) {
    __shared__ float As[32][68];   // padded: transpose stores, float4-aligned reads
    __shared__ float Bs[32][64];
    const int b  = blockIdx.z;
    const int m0 = blockIdx.y * 64;    // l
    const int n0 = blockIdx.x * 64;    // c
    const int t  = threadIdx.x;
    const int tx = t & 15, ty = t >> 4;

    float acc[4][4];
#pragma unroll
    for (int i = 0; i < 4; ++i)
#pragma unroll
        for (int j = 0; j < 4; ++j) acc[i][j] = 0.f;

    for (int k0 = 0; k0 < DI; k0 += 32) {
#pragma unroll
        for (int i = 0; i < 2; ++i) {
            int slot = t + i * 256;
            // A tile: 64 m-rows x 32 k, transpose into As[k][m]
            int m  = slot >> 3;            // 0..63
            int kq = (slot & 7) << 2;      // 0..28
            float4 v = *(const float4*)(y + ((size_t)b * LSEQ + m0 + m) * DI + k0 + kq);
            As[kq + 0][m] = v.x;
            As[kq + 1][m] = v.y;
            As[kq + 2][m] = v.z;
            As[kq + 3][m] = v.w;
            // B tile
            int kc = slot >> 4;
            int p4 = (slot & 15) << 2;
            *(float4*)(&Bs[kc][p4]) =
                *(const float4*)(W + (size_t)(k0 + kc) * DM + n0 + p4);
        }
        __syncthreads();
#pragma unroll
        for (int k = 0; k < 32; ++k) {
            float a[4], bb[4];
            *(float4*)(a)  = *(float4*)(&As[k][ty * 4]);
            *(float4*)(bb) = *(float4*)(&Bs[k][tx * 4]);
#pragma unroll
            for (int i = 0; i < 4; ++i)
#pragma unroll
                for (int j = 0; j < 4; ++j) acc[i][j] = fmaf(a[i], bb[j], acc[i][j]);
        }
        __syncthreads();
    }
#pragma unroll
    for (int j = 0; j < 4; ++j) {
        int c = n0 + tx * 4 + j;
        float* ocol = out + ((size_t)b * DM + c) * LSEQ + m0;
        *(float4*)(ocol + ty * 4) = make_float4(acc[0][j], acc[1][j], acc[2][j], acc[3][j]);
    }
}

extern "C" void kernel_launch(void* const* d_in, const int* in_sizes, int n_in,
                              void* d_out, int out_size, void* d_ws, size_t ws_size,
                              hipStream_t stream) {
    const float* x      = (const float*)d_in[0];
    const float* W_in   = (const float*)d_in[1];
    const float* conv_w = (const float*)d_in[2];
    const float* conv_b = (const float*)d_in[3];
    const float* W_x    = (const float*)d_in[4];
    const float* W_dt   = (const float*)d_in[5];
    const float* b_dt   = (const float*)d_in[6];
    const float* A_log  = (const float*)d_in[7];
    const float* Dw     = (const float*)d_in[8];
    const float* W_out  = (const float*)d_in[9];
    float* out = (float*)d_out;

    float* ws   = (float*)d_ws;
    float* xz   = ws;                    // B*L*512            = 4,194,304
    float* xc   = xz + 4194304;          // B*L*256            = 2,097,152
    float* bc   = xc + 2097152;          // B*L*32             =   262,144
    float* dtb  = bc + 262144;           // B*L*256            = 2,097,152
    float* Pst  = dtb + 2097152;         // B*DI*NCHUNK*DS     = 1,048,576
    float* Fst  = Pst + 1048576;         // 1,048,576 (carry written in-place)
    float* yb   = Fst + 1048576;         // B*L*DI             = 2,097,152

    gemm_in_k  <<<dim3(8, 64, BSZ), 256, 0, stream>>>(x, W_in, xz);
    convx_k    <<<dim3(BSZ * LSEQ), 256, 0, stream>>>(xz, conv_w, conv_b, W_x, W_dt, b_dt,
                                                      xc, bc, dtb);
    scan_a_k   <<<dim3(BSZ * NCHUNK), 256, 0, stream>>>(dtb, xc, bc, A_log, Pst, Fst);
    scan_b_k   <<<dim3(BSZ * DI * DS / 256), 256, 0, stream>>>(Pst, Fst);
    scan_c_k   <<<dim3(BSZ * NCHUNK), 256, 0, stream>>>(dtb, xc, bc, xz, A_log, Dw, Fst, yb);
    gemm_out_k <<<dim3(4, 64, BSZ), 256, 0, stream>>>(yb, W_out, out);
}

// Round 4
// 214.353 us; speedup vs baseline: 1.3768x; 1.0483x over previous
//
#include <hip/hip_runtime.h>
#include <math.h>

#define BSZ 2
#define LSEQ 4096
#define DM 256      // d_model
#define DI 256      // d_inner
#define DS 16       // d_state
#define DR 16       // dt_rank
#define NIN 512     // 2*DI
#define NCHUNK 128
#define LCHUNK 32
#define NB2 320     // padded Bcat width (288 real: 256 dt + 32 bc)

__device__ __forceinline__ float sigmoid_f(float v) {
    return __builtin_amdgcn_rcpf(1.0f + __expf(-v));
}

// ---------------- gemm_in: xz[b,l,n] = sum_c x[b,c,l] * W_in[c,n] ----------------
__global__ __launch_bounds__(256) void gemm_in_k(const float* __restrict__ x,
                                                 const float* __restrict__ W,
                                                 float* __restrict__ xz) {
    __shared__ float As[32][64];
    __shared__ float Bs[32][64];
    const int b  = blockIdx.z;
    const int m0 = blockIdx.y * 64;
    const int n0 = blockIdx.x * 64;
    const int t  = threadIdx.x;
    const int tx = t & 15, ty = t >> 4;

    float acc[4][4];
#pragma unroll
    for (int i = 0; i < 4; ++i)
#pragma unroll
        for (int j = 0; j < 4; ++j) acc[i][j] = 0.f;

    for (int k0 = 0; k0 < DM; k0 += 32) {
#pragma unroll
        for (int i = 0; i < 2; ++i) {
            int slot = t + i * 256;
            int kc = slot >> 4;
            int p4 = (slot & 15) << 2;
            *(float4*)(&As[kc][p4]) =
                *(const float4*)(x + ((size_t)b * DM + k0 + kc) * LSEQ + m0 + p4);
            *(float4*)(&Bs[kc][p4]) =
                *(const float4*)(W + (size_t)(k0 + kc) * NIN + n0 + p4);
        }
        __syncthreads();
#pragma unroll
        for (int k = 0; k < 32; ++k) {
            float a[4], bb[4];
            *(float4*)(a)  = *(float4*)(&As[k][ty * 4]);
            *(float4*)(bb) = *(float4*)(&Bs[k][tx * 4]);
#pragma unroll
            for (int i = 0; i < 4; ++i)
#pragma unroll
                for (int j = 0; j < 4; ++j) acc[i][j] = fmaf(a[i], bb[j], acc[i][j]);
        }
        __syncthreads();
    }
#pragma unroll
    for (int i = 0; i < 4; ++i) {
        int m = m0 + ty * 4 + i;
        float* orow = xz + ((size_t)b * LSEQ + m) * NIN + n0;
        *(float4*)(orow + tx * 4) = make_float4(acc[i][0], acc[i][1], acc[i][2], acc[i][3]);
    }
}

// ---------------- conv + silu (vectorized, standalone): xc[b,l,d] ----------------
__global__ __launch_bounds__(256) void conv_silu_k(const float* __restrict__ xz,
                                                   const float* __restrict__ conv_w,
                                                   const float* __restrict__ conv_b,
                                                   float* __restrict__ xc) {
    const int t   = threadIdx.x;
    const int idx = blockIdx.x * 4 + (t >> 6);    // m = b*L + l, 0..8191
    const int b   = idx >> 12;
    const int l   = idx & (LSEQ - 1);
    const int dq  = (t & 63) << 2;

    float4 cw0 = *(const float4*)(conv_w + (dq + 0) * 4);
    float4 cw1 = *(const float4*)(conv_w + (dq + 1) * 4);
    float4 cw2 = *(const float4*)(conv_w + (dq + 2) * 4);
    float4 cw3 = *(const float4*)(conv_w + (dq + 3) * 4);
    const float* cwp0 = (const float*)&cw0;
    const float* cwp1 = (const float*)&cw1;
    const float* cwp2 = (const float*)&cw2;
    const float* cwp3 = (const float*)&cw3;

    float4 acc = *(const float4*)(conv_b + dq);
#pragma unroll
    for (int k = 0; k < 4; ++k) {
        int ls = l - 3 + k;
        if (ls >= 0) {
            float4 v = *(const float4*)(xz + ((size_t)b * LSEQ + ls) * NIN + dq);
            acc.x = fmaf(v.x, cwp0[k], acc.x);
            acc.y = fmaf(v.y, cwp1[k], acc.y);
            acc.z = fmaf(v.z, cwp2[k], acc.z);
            acc.w = fmaf(v.w, cwp3[k], acc.w);
        }
    }
    acc.x *= sigmoid_f(acc.x);
    acc.y *= sigmoid_f(acc.y);
    acc.z *= sigmoid_f(acc.z);
    acc.w *= sigmoid_f(acc.w);
    *(float4*)(xc + (size_t)idx * DI + dq) = acc;
}

// ---------------- bcat: Bcat[c][0:256]=W_x[:, :16]@W_dt, [256:288]=W_x[:,16:48], [288:320]=0 ----------------
__global__ __launch_bounds__(320) void bcat_k(const float* __restrict__ W_x,
                                              const float* __restrict__ W_dt,
                                              float* __restrict__ Bcat) {
    __shared__ float wr[16];
    const int c = blockIdx.x;
    const int t = threadIdx.x;
    if (t < 16) wr[t] = W_x[(size_t)c * 48 + t];
    __syncthreads();
    if (t < 256) {
        float acc = 0.f;
#pragma unroll
        for (int r = 0; r < 16; ++r) acc = fmaf(wr[r], W_dt[r * DI + t], acc);
        Bcat[(size_t)c * NB2 + t] = acc;
    } else if (t < 288) {
        Bcat[(size_t)c * NB2 + t] = W_x[(size_t)c * 48 + 16 + (t - 256)];
    } else {
        Bcat[(size_t)c * NB2 + t] = 0.f;
    }
}

// ---------------- gemm_x2: [dt | bc] = xc @ Bcat ; dt gets softplus(.+b_dt) ----------------
__global__ __launch_bounds__(256) void gemm_x2_k(const float* __restrict__ xc,
                                                 const float* __restrict__ Bcat,
                                                 const float* __restrict__ b_dt,
                                                 float* __restrict__ dt,
                                                 float* __restrict__ bc) {
    __shared__ float As[32][68];
    __shared__ float Bs[32][64];
    const int m0 = blockIdx.y * 64;
    const int n0 = blockIdx.x * 64;
    const int t  = threadIdx.x;
    const int tx = t & 15, ty = t >> 4;

    float acc[4][4];
#pragma unroll
    for (int i = 0; i < 4; ++i)
#pragma unroll
        for (int j = 0; j < 4; ++j) acc[i][j] = 0.f;

    for (int k0 = 0; k0 < DI; k0 += 32) {
#pragma unroll
        for (int i = 0; i < 2; ++i) {
            int slot = t + i * 256;
            int m  = slot >> 3;
            int kq = (slot & 7) << 2;
            float4 v = *(const float4*)(xc + (size_t)(m0 + m) * DI + k0 + kq);
            As[kq + 0][m] = v.x;
            As[kq + 1][m] = v.y;
            As[kq + 2][m] = v.z;
            As[kq + 3][m] = v.w;
            int kc = slot >> 4;
            int p4 = (slot & 15) << 2;
            *(float4*)(&Bs[kc][p4]) =
                *(const float4*)(Bcat + (size_t)(k0 + kc) * NB2 + n0 + p4);
        }
        __syncthreads();
#pragma unroll
        for (int k = 0; k < 32; ++k) {
            float a[4], bb[4];
            *(float4*)(a)  = *(float4*)(&As[k][ty * 4]);
            *(float4*)(bb) = *(float4*)(&Bs[k][tx * 4]);
#pragma unroll
            for (int i = 0; i < 4; ++i)
#pragma unroll
                for (int j = 0; j < 4; ++j) acc[i][j] = fmaf(a[i], bb[j], acc[i][j]);
        }
        __syncthreads();
    }

    const int n = n0 + tx * 4;
    if (n < 256) {
        float4 bd = *(const float4*)(b_dt + n);
        const float* bdp = (const float*)&bd;
#pragma unroll
        for (int i = 0; i < 4; ++i) {
            int m = m0 + ty * 4 + i;
            float v[4];
#pragma unroll
            for (int j = 0; j < 4; ++j) {
                float a2 = acc[i][j] + bdp[j];
                v[j] = fmaxf(a2, 0.f) + log1pf(expf(-fabsf(a2)));
            }
            *(float4*)(dt + (size_t)m * DI + n) = make_float4(v[0], v[1], v[2], v[3]);
        }
    } else if (n < 288) {
#pragma unroll
        for (int i = 0; i < 4; ++i) {
            int m = m0 + ty * 4 + i;
            *(float4*)(bc + (size_t)m * 32 + (n - 256)) =
                make_float4(acc[i][0], acc[i][1], acc[i][2], acc[i][3]);
        }
    }
}

// ---------------- scan phase A ----------------
__global__ __launch_bounds__(256) void scan_a_k(const float* __restrict__ dt,
                                                const float* __restrict__ xc,
                                                const float* __restrict__ bc,
                                                const float* __restrict__ A_log,
                                                float* __restrict__ Pst,
                                                float* __restrict__ Fst) {
    __shared__ float Bl[LCHUNK][16];
    const int blk   = blockIdx.x;
    const int b     = blk >> 7;
    const int chunk = blk & (NCHUNK - 1);
    const int d     = threadIdx.x;
    const int l0    = chunk * LCHUNK;

    if (d < LCHUNK * 4) {
        int l = d >> 2, q = d & 3;
        *(float4*)(&Bl[l][q * 4]) =
            *(const float4*)(bc + (size_t)(b * LSEQ + l0 + l) * 32 + q * 4);
    }
    float Ads[16];
#pragma unroll
    for (int s = 0; s < 16; ++s) Ads[s] = -expf(A_log[d * DS + s]);
    __syncthreads();

    float h[16], P[16];
#pragma unroll
    for (int s = 0; s < 16; ++s) { h[s] = 0.f; P[s] = 1.f; }

    const float* dtp = dt + ((size_t)b * LSEQ + l0) * DI + d;
    const float* xcp = xc + ((size_t)b * LSEQ + l0) * DI + d;

#pragma unroll 4
    for (int i = 0; i < LCHUNK; ++i) {
        float dtv = dtp[(size_t)i * DI];
        float xcv = xcp[(size_t)i * DI];
        float du  = dtv * xcv;
        float4 b0 = *(float4*)(&Bl[i][0]);
        float4 b1 = *(float4*)(&Bl[i][4]);
        float4 b2 = *(float4*)(&Bl[i][8]);
        float4 b3 = *(float4*)(&Bl[i][12]);
        float bv[16] = {b0.x,b0.y,b0.z,b0.w, b1.x,b1.y,b1.z,b1.w,
                        b2.x,b2.y,b2.z,b2.w, b3.x,b3.y,b3.z,b3.w};
#pragma unroll
        for (int s = 0; s < 16; ++s) {
            float a = __expf(dtv * Ads[s]);
            h[s] = fmaf(h[s], a, du * bv[s]);
            P[s] *= a;
        }
    }
    size_t base = ((size_t)(b * DI + d) * NCHUNK + chunk) * DS;
#pragma unroll
    for (int q = 0; q < 4; ++q) {
        *(float4*)(Pst + base + q * 4) = make_float4(P[q*4], P[q*4+1], P[q*4+2], P[q*4+3]);
        *(float4*)(Fst + base + q * 4) = make_float4(h[q*4], h[q*4+1], h[q*4+2], h[q*4+3]);
    }
}

// ---------------- scan phase B ----------------
__global__ __launch_bounds__(256) void scan_b_k(const float* __restrict__ Pst,
                                                float* __restrict__ Fst) {
    const int t = blockIdx.x * 256 + threadIdx.x;
    const int s = t & 15;
    const int d = (t >> 4) & (DI - 1);
    const int b = t >> 12;
    size_t base = ((size_t)(b * DI + d) * NCHUNK) * DS + s;
    float st = 0.f;
#pragma unroll 8
    for (int c = 0; c < NCHUNK; ++c) {
        size_t idx = base + (size_t)c * DS;
        float P = Pst[idx];
        float F = Fst[idx];
        Fst[idx] = st;
        st = fmaf(P, st, F);
    }
}

// ---------------- scan phase C ----------------
__global__ __launch_bounds__(256) void scan_c_k(const float* __restrict__ dt,
                                                const float* __restrict__ xc,
                                                const float* __restrict__ bc,
                                                const float* __restrict__ xz,
                                                const float* __restrict__ A_log,
                                                const float* __restrict__ Dw,
                                                const float* __restrict__ carry,
                                                float* __restrict__ y) {
    __shared__ float BC[LCHUNK][32];
    const int blk   = blockIdx.x;
    const int b     = blk >> 7;
    const int chunk = blk & (NCHUNK - 1);
    const int d     = threadIdx.x;
    const int l0    = chunk * LCHUNK;

    {
        int l = d >> 3, q = d & 7;
        *(float4*)(&BC[l][q * 4]) =
            *(const float4*)(bc + (size_t)(b * LSEQ + l0 + l) * 32 + q * 4);
    }
    float Ads[16];
#pragma unroll
    for (int s = 0; s < 16; ++s) Ads[s] = -expf(A_log[d * DS + s]);
    const float Dd = Dw[d];

    float h[16];
    size_t cbase = ((size_t)(b * DI + d) * NCHUNK + chunk) * DS;
#pragma unroll
    for (int q = 0; q < 4; ++q) {
        float4 c4 = *(const float4*)(carry + cbase + q * 4);
        h[q*4] = c4.x; h[q*4+1] = c4.y; h[q*4+2] = c4.z; h[q*4+3] = c4.w;
    }
    __syncthreads();

    const float* dtp = dt + ((size_t)b * LSEQ + l0) * DI + d;
    const float* xcp = xc + ((size_t)b * LSEQ + l0) * DI + d;
    const float* zp  = xz + ((size_t)b * LSEQ + l0) * NIN + DI + d;
    float* yout      = y  + ((size_t)b * LSEQ + l0) * DI + d;

#pragma unroll 4
    for (int i = 0; i < LCHUNK; ++i) {
        float dtv = dtp[(size_t)i * DI];
        float xcv = xcp[(size_t)i * DI];
        float zv  = zp[(size_t)i * NIN];
        float du  = dtv * xcv;
        float4 b0 = *(float4*)(&BC[i][0]);
        float4 b1 = *(float4*)(&BC[i][4]);
        float4 b2 = *(float4*)(&BC[i][8]);
        float4 b3 = *(float4*)(&BC[i][12]);
        float4 c0 = *(float4*)(&BC[i][16]);
        float4 c1 = *(float4*)(&BC[i][20]);
        float4 c2 = *(float4*)(&BC[i][24]);
        float4 c3 = *(float4*)(&BC[i][28]);
        float bv[16] = {b0.x,b0.y,b0.z,b0.w, b1.x,b1.y,b1.z,b1.w,
                        b2.x,b2.y,b2.z,b2.w, b3.x,b3.y,b3.z,b3.w};
        float cv[16] = {c0.x,c0.y,c0.z,c0.w, c1.x,c1.y,c1.z,c1.w,
                        c2.x,c2.y,c2.z,c2.w, c3.x,c3.y,c3.z,c3.w};
        float yv = 0.f;
#pragma unroll
        for (int s = 0; s < 16; ++s) {
            float a = __expf(dtv * Ads[s]);
            h[s] = fmaf(h[s], a, du * bv[s]);
            yv = fmaf(h[s], cv[s], yv);
        }
        float yf = fmaf(xcv, Dd, yv);
        yout[(size_t)i * DI] = yf * (zv * sigmoid_f(zv));
    }
}

// ---------------- gemm_out: out[b,c,l] = sum_d y[b,l,d] * W_out[d,c] ----------------
__global__ __launch_bounds__(256) void gemm_out_k(const float* __restrict__ y,
                                                  const float* __restrict__ W,
                                                  float* __restrict__ out) {
    __shared__ float As[32][68];
    __shared__ float Bs[32][64];
    const int b  = blockIdx.z;
    const int m0 = blockIdx.y * 64;
    const int n0 = blockIdx.x * 64;
    const int t  = threadIdx.x;
    const int tx = t & 15, ty = t >> 4;

    float acc[4][4];
#pragma unroll
    for (int i = 0; i < 4; ++i)
#pragma unroll
        for (int j = 0; j < 4; ++j) acc[i][j] = 0.f;

    for (int k0 = 0; k0 < DI; k0 += 32) {
#pragma unroll
        for (int i = 0; i < 2; ++i) {
            int slot = t + i * 256;
            int m  = slot >> 3;
            int kq = (slot & 7) << 2;
            float4 v = *(const float4*)(y + ((size_t)b * LSEQ + m0 + m) * DI + k0 + kq);
            As[kq + 0][m] = v.x;
            As[kq + 1][m] = v.y;
            As[kq + 2][m] = v.z;
            As[kq + 3][m] = v.w;
            int kc = slot >> 4;
            int p4 = (slot & 15) << 2;
            *(float4*)(&Bs[kc][p4]) =
                *(const float4*)(W + (size_t)(k0 + kc) * DM + n0 + p4);
        }
        __syncthreads();
#pragma unroll
        for (int k = 0; k < 32; ++k) {
            float a[4], bb[4];
            *(float4*)(a)  = *(float4*)(&As[k][ty * 4]);
            *(float4*)(bb) = *(float4*)(&Bs[k][tx * 4]);
#pragma unroll
            for (int i = 0; i < 4; ++i)
#pragma unroll
                for (int j = 0; j < 4; ++j) acc[i][j] = fmaf(a[i], bb[j], acc[i][j]);
        }
        __syncthreads();
    }
#pragma unroll
    for (int j = 0; j < 4; ++j) {
        int c = n0 + tx * 4 + j;
        float* ocol = out + ((size_t)b * DM + c) * LSEQ + m0;
        *(float4*)(ocol + ty * 4) = make_float4(acc[0][j], acc[1][j], acc[2][j], acc[3][j]);
    }
}

extern "C" void kernel_launch(void* const* d_in, const int* in_sizes, int n_in,
                              void* d_out, int out_size, void* d_ws, size_t ws_size,
                              hipStream_t stream) {
    const float* x      = (const float*)d_in[0];
    const float* W_in   = (const float*)d_in[1];
    const float* conv_w = (const float*)d_in[2];
    const float* conv_b = (const float*)d_in[3];
    const float* W_x    = (const float*)d_in[4];
    const float* W_dt   = (const float*)d_in[5];
    const float* b_dt   = (const float*)d_in[6];
    const float* A_log  = (const float*)d_in[7];
    const float* Dw     = (const float*)d_in[8];
    const float* W_out  = (const float*)d_in[9];
    float* out = (float*)d_out;

    float* ws   = (float*)d_ws;
    float* xz   = ws;                    // B*L*512            = 4,194,304
    float* xc   = xz + 4194304;          // B*L*256            = 2,097,152
    float* bc   = xc + 2097152;          // B*L*32             =   262,144
    float* dtb  = bc + 262144;           // B*L*256            = 2,097,152
    float* Pst  = dtb + 2097152;         // B*DI*NCHUNK*DS     = 1,048,576
    float* Fst  = Pst + 1048576;         // 1,048,576
    float* yb   = Fst + 1048576;         // B*L*DI             = 2,097,152
    float* Bcat = yb + 2097152;          // 256*320            =    81,920

    bcat_k     <<<dim3(256), 320, 0, stream>>>(W_x, W_dt, Bcat);
    gemm_in_k  <<<dim3(8, 64, BSZ), 256, 0, stream>>>(x, W_in, xz);
    conv_silu_k<<<dim3(BSZ * LSEQ / 4), 256, 0, stream>>>(xz, conv_w, conv_b, xc);
    gemm_x2_k  <<<dim3(5, 128), 256, 0, stream>>>(xc, Bcat, b_dt, dtb, bc);
    scan_a_k   <<<dim3(BSZ * NCHUNK), 256, 0, stream>>>(dtb, xc, bc, A_log, Pst, Fst);
    scan_b_k   <<<dim3(BSZ * DI * DS / 256), 256, 0, stream>>>(Pst, Fst);
    scan_c_k   <<<dim3(BSZ * NCHUNK), 256, 0, stream>>>(dtb, xc, bc, xz, A_log, Dw, Fst, yb);
    gemm_out_k <<<dim3(4, 64, BSZ), 256, 0, stream>>>(yb, W_out, out);
}

// Round 5
// 197.139 us; speedup vs baseline: 1.4970x; 1.0873x over previous
//
#include <hip/hip_runtime.h>
#include <math.h>

#define BSZ 2
#define LSEQ 4096
#define DM 256      // d_model
#define DI 256      // d_inner
#define DS 16       // d_state
#define DR 16       // dt_rank
#define NIN 512     // 2*DI
#define NCHUNK 128
#define LCHUNK 32
#define NB2 320     // padded Bcat width (288 real: 256 dt + 32 bc)

typedef __attribute__((ext_vector_type(8))) short short8;
typedef __attribute__((ext_vector_type(4))) float floatx4;

__device__ __forceinline__ float sigmoid_f(float v) {
    return __builtin_amdgcn_rcpf(1.0f + __expf(-v));
}

__device__ __forceinline__ unsigned int bf16_rne(float v) {
    unsigned int u = __float_as_uint(v);
    return (u + 0x7FFFu + ((u >> 16) & 1u)) >> 16;
}

// ---------------- gemm_in (MFMA bf16x3): xz[b,l,n] = sum_c x[b,c,l] * W_in[c,n] ----------------
// 64x64 tile, 4 waves each computing 32x32 as 2x2 of 16x16x32 frags, 3-pass split-bf16.
__global__ __launch_bounds__(256) void gemm_in_k(const float* __restrict__ x,
                                                 const float* __restrict__ W,
                                                 float* __restrict__ xz) {
    __shared__ unsigned short sA[128][40];   // rows 0-63 hi, 64-127 lo; k 0..31 (pad 40)
    __shared__ unsigned short sB[128][40];
    const int b  = blockIdx.z;
    const int m0 = blockIdx.y * 64;
    const int n0 = blockIdx.x * 64;
    const int t  = threadIdx.x;
    const int w    = t >> 6;
    const int lane = t & 63;
    const int kp = t & 15;     // k-pair index 0..15  (k = 2kp, 2kp+1)
    const int g  = t >> 4;     // row-group 0..15 (4 rows each)

    const int mwb = (w & 1) * 32;   // wave m offset in tile
    const int nwb = (w >> 1) * 32;  // wave n offset in tile
    const int fr  = lane & 15;      // frag row (m or n)
    const int q   = lane >> 4;      // frag k-quad

    floatx4 acc[2][2];
#pragma unroll
    for (int mi = 0; mi < 2; ++mi)
#pragma unroll
        for (int ni = 0; ni < 2; ++ni) acc[mi][ni] = (floatx4){0.f, 0.f, 0.f, 0.f};

    for (int k0 = 0; k0 < DM; k0 += 32) {
        // ---- stage A: x rows (k), m-contiguous ----
        {
            const float* pa = x + ((size_t)b * DM + k0 + 2 * kp) * LSEQ + m0 + 4 * g;
            float4 fa0 = *(const float4*)(pa);
            float4 fa1 = *(const float4*)(pa + LSEQ);
            const float* a0 = (const float*)&fa0;
            const float* a1 = (const float*)&fa1;
#pragma unroll
            for (int j = 0; j < 4; ++j) {
                int m = 4 * g + j;
                unsigned int h0 = bf16_rne(a0[j]);
                unsigned int h1 = bf16_rne(a1[j]);
                float r0 = a0[j] - __uint_as_float(h0 << 16);
                float r1 = a1[j] - __uint_as_float(h1 << 16);
                unsigned int l0 = bf16_rne(r0);
                unsigned int l1 = bf16_rne(r1);
                *(unsigned int*)&sA[m][2 * kp]      = h0 | (h1 << 16);
                *(unsigned int*)&sA[64 + m][2 * kp] = l0 | (l1 << 16);
            }
            // ---- stage B: W rows (k), n-contiguous ----
            const float* pb = W + (size_t)(k0 + 2 * kp) * NIN + n0 + 4 * g;
            float4 fb0 = *(const float4*)(pb);
            float4 fb1 = *(const float4*)(pb + NIN);
            const float* b0 = (const float*)&fb0;
            const float* b1 = (const float*)&fb1;
#pragma unroll
            for (int j = 0; j < 4; ++j) {
                int n = 4 * g + j;
                unsigned int h0 = bf16_rne(b0[j]);
                unsigned int h1 = bf16_rne(b1[j]);
                float r0 = b0[j] - __uint_as_float(h0 << 16);
                float r1 = b1[j] - __uint_as_float(h1 << 16);
                unsigned int l0 = bf16_rne(r0);
                unsigned int l1 = bf16_rne(r1);
                *(unsigned int*)&sB[n][2 * kp]      = h0 | (h1 << 16);
                *(unsigned int*)&sB[64 + n][2 * kp] = l0 | (l1 << 16);
            }
        }
        __syncthreads();

        short8 ah[2], al[2], bh[2], bl[2];
#pragma unroll
        for (int mi = 0; mi < 2; ++mi) {
            int mr = mwb + mi * 16 + fr;
            ah[mi] = *(const short8*)&sA[mr][q * 8];
            al[mi] = *(const short8*)&sA[64 + mr][q * 8];
        }
#pragma unroll
        for (int ni = 0; ni < 2; ++ni) {
            int nr = nwb + ni * 16 + fr;
            bh[ni] = *(const short8*)&sB[nr][q * 8];
            bl[ni] = *(const short8*)&sB[64 + nr][q * 8];
        }
#pragma unroll
        for (int mi = 0; mi < 2; ++mi)
#pragma unroll
            for (int ni = 0; ni < 2; ++ni) {
                acc[mi][ni] = __builtin_amdgcn_mfma_f32_16x16x32_bf16(ah[mi], bh[ni], acc[mi][ni], 0, 0, 0);
                acc[mi][ni] = __builtin_amdgcn_mfma_f32_16x16x32_bf16(ah[mi], bl[ni], acc[mi][ni], 0, 0, 0);
                acc[mi][ni] = __builtin_amdgcn_mfma_f32_16x16x32_bf16(al[mi], bh[ni], acc[mi][ni], 0, 0, 0);
            }
        __syncthreads();
    }

    // epilogue: C/D layout col=lane&15 (n), row=quad*4+reg (m)
#pragma unroll
    for (int mi = 0; mi < 2; ++mi)
#pragma unroll
        for (int ni = 0; ni < 2; ++ni) {
#pragma unroll
            for (int r = 0; r < 4; ++r) {
                int m = m0 + mwb + mi * 16 + q * 4 + r;
                int n = n0 + nwb + ni * 16 + fr;
                xz[((size_t)b * LSEQ + m) * NIN + n] = acc[mi][ni][r];
            }
        }
}

// ---------------- conv + silu (vectorized, standalone): xc[b,l,d] ----------------
__global__ __launch_bounds__(256) void conv_silu_k(const float* __restrict__ xz,
                                                   const float* __restrict__ conv_w,
                                                   const float* __restrict__ conv_b,
                                                   float* __restrict__ xc) {
    const int t   = threadIdx.x;
    const int idx = blockIdx.x * 4 + (t >> 6);    // m = b*L + l, 0..8191
    const int b   = idx >> 12;
    const int l   = idx & (LSEQ - 1);
    const int dq  = (t & 63) << 2;

    float4 cw0 = *(const float4*)(conv_w + (dq + 0) * 4);
    float4 cw1 = *(const float4*)(conv_w + (dq + 1) * 4);
    float4 cw2 = *(const float4*)(conv_w + (dq + 2) * 4);
    float4 cw3 = *(const float4*)(conv_w + (dq + 3) * 4);
    const float* cwp0 = (const float*)&cw0;
    const float* cwp1 = (const float*)&cw1;
    const float* cwp2 = (const float*)&cw2;
    const float* cwp3 = (const float*)&cw3;

    float4 acc = *(const float4*)(conv_b + dq);
#pragma unroll
    for (int k = 0; k < 4; ++k) {
        int ls = l - 3 + k;
        if (ls >= 0) {
            float4 v = *(const float4*)(xz + ((size_t)b * LSEQ + ls) * NIN + dq);
            acc.x = fmaf(v.x, cwp0[k], acc.x);
            acc.y = fmaf(v.y, cwp1[k], acc.y);
            acc.z = fmaf(v.z, cwp2[k], acc.z);
            acc.w = fmaf(v.w, cwp3[k], acc.w);
        }
    }
    acc.x *= sigmoid_f(acc.x);
    acc.y *= sigmoid_f(acc.y);
    acc.z *= sigmoid_f(acc.z);
    acc.w *= sigmoid_f(acc.w);
    *(float4*)(xc + (size_t)idx * DI + dq) = acc;
}

// ---------------- bcat: Bcat[c][0:256]=W_x[:, :16]@W_dt, [256:288]=W_x[:,16:48], [288:320]=0 ----------------
__global__ __launch_bounds__(320) void bcat_k(const float* __restrict__ W_x,
                                              const float* __restrict__ W_dt,
                                              float* __restrict__ Bcat) {
    __shared__ float wr[16];
    const int c = blockIdx.x;
    const int t = threadIdx.x;
    if (t < 16) wr[t] = W_x[(size_t)c * 48 + t];
    __syncthreads();
    if (t < 256) {
        float acc = 0.f;
#pragma unroll
        for (int r = 0; r < 16; ++r) acc = fmaf(wr[r], W_dt[r * DI + t], acc);
        Bcat[(size_t)c * NB2 + t] = acc;
    } else if (t < 288) {
        Bcat[(size_t)c * NB2 + t] = W_x[(size_t)c * 48 + 16 + (t - 256)];
    } else {
        Bcat[(size_t)c * NB2 + t] = 0.f;
    }
}

// ---------------- gemm_x2: [dt | bc] = xc @ Bcat ; dt gets softplus(.+b_dt) ----------------
__global__ __launch_bounds__(256) void gemm_x2_k(const float* __restrict__ xc,
                                                 const float* __restrict__ Bcat,
                                                 const float* __restrict__ b_dt,
                                                 float* __restrict__ dt,
                                                 float* __restrict__ bc) {
    __shared__ float As[32][68];
    __shared__ float Bs[32][64];
    const int m0 = blockIdx.y * 64;
    const int n0 = blockIdx.x * 64;
    const int t  = threadIdx.x;
    const int tx = t & 15, ty = t >> 4;

    float acc[4][4];
#pragma unroll
    for (int i = 0; i < 4; ++i)
#pragma unroll
        for (int j = 0; j < 4; ++j) acc[i][j] = 0.f;

    for (int k0 = 0; k0 < DI; k0 += 32) {
#pragma unroll
        for (int i = 0; i < 2; ++i) {
            int slot = t + i * 256;
            int m  = slot >> 3;
            int kq = (slot & 7) << 2;
            float4 v = *(const float4*)(xc + (size_t)(m0 + m) * DI + k0 + kq);
            As[kq + 0][m] = v.x;
            As[kq + 1][m] = v.y;
            As[kq + 2][m] = v.z;
            As[kq + 3][m] = v.w;
            int kc = slot >> 4;
            int p4 = (slot & 15) << 2;
            *(float4*)(&Bs[kc][p4]) =
                *(const float4*)(Bcat + (size_t)(k0 + kc) * NB2 + n0 + p4);
        }
        __syncthreads();
#pragma unroll
        for (int k = 0; k < 32; ++k) {
            float a[4], bb[4];
            *(float4*)(a)  = *(float4*)(&As[k][ty * 4]);
            *(float4*)(bb) = *(float4*)(&Bs[k][tx * 4]);
#pragma unroll
            for (int i = 0; i < 4; ++i)
#pragma unroll
                for (int j = 0; j < 4; ++j) acc[i][j] = fmaf(a[i], bb[j], acc[i][j]);
        }
        __syncthreads();
    }

    const int n = n0 + tx * 4;
    if (n < 256) {
        float4 bd = *(const float4*)(b_dt + n);
        const float* bdp = (const float*)&bd;
#pragma unroll
        for (int i = 0; i < 4; ++i) {
            int m = m0 + ty * 4 + i;
            float v[4];
#pragma unroll
            for (int j = 0; j < 4; ++j) {
                float a2 = acc[i][j] + bdp[j];
                v[j] = fmaxf(a2, 0.f) + log1pf(expf(-fabsf(a2)));
            }
            *(float4*)(dt + (size_t)m * DI + n) = make_float4(v[0], v[1], v[2], v[3]);
        }
    } else if (n < 288) {
#pragma unroll
        for (int i = 0; i < 4; ++i) {
            int m = m0 + ty * 4 + i;
            *(float4*)(bc + (size_t)m * 32 + (n - 256)) =
                make_float4(acc[i][0], acc[i][1], acc[i][2], acc[i][3]);
        }
    }
}

// ---------------- scan phase A ----------------
__global__ __launch_bounds__(256) void scan_a_k(const float* __restrict__ dt,
                                                const float* __restrict__ xc,
                                                const float* __restrict__ bc,
                                                const float* __restrict__ A_log,
                                                float* __restrict__ Pst,
                                                float* __restrict__ Fst) {
    __shared__ float Bl[LCHUNK][16];
    const int blk   = blockIdx.x;
    const int b     = blk >> 7;
    const int chunk = blk & (NCHUNK - 1);
    const int d     = threadIdx.x;
    const int l0    = chunk * LCHUNK;

    if (d < LCHUNK * 4) {
        int l = d >> 2, q = d & 3;
        *(float4*)(&Bl[l][q * 4]) =
            *(const float4*)(bc + (size_t)(b * LSEQ + l0 + l) * 32 + q * 4);
    }
    float Ads[16];
#pragma unroll
    for (int s = 0; s < 16; ++s) Ads[s] = -expf(A_log[d * DS + s]);
    __syncthreads();

    float h[16], P[16];
#pragma unroll
    for (int s = 0; s < 16; ++s) { h[s] = 0.f; P[s] = 1.f; }

    const float* dtp = dt + ((size_t)b * LSEQ + l0) * DI + d;
    const float* xcp = xc + ((size_t)b * LSEQ + l0) * DI + d;

#pragma unroll 4
    for (int i = 0; i < LCHUNK; ++i) {
        float dtv = dtp[(size_t)i * DI];
        float xcv = xcp[(size_t)i * DI];
        float du  = dtv * xcv;
        float4 b0 = *(float4*)(&Bl[i][0]);
        float4 b1 = *(float4*)(&Bl[i][4]);
        float4 b2 = *(float4*)(&Bl[i][8]);
        float4 b3 = *(float4*)(&Bl[i][12]);
        float bv[16] = {b0.x,b0.y,b0.z,b0.w, b1.x,b1.y,b1.z,b1.w,
                        b2.x,b2.y,b2.z,b2.w, b3.x,b3.y,b3.z,b3.w};
#pragma unroll
        for (int s = 0; s < 16; ++s) {
            float a = __expf(dtv * Ads[s]);
            h[s] = fmaf(h[s], a, du * bv[s]);
            P[s] *= a;
        }
    }
    size_t base = ((size_t)(b * DI + d) * NCHUNK + chunk) * DS;
#pragma unroll
    for (int q = 0; q < 4; ++q) {
        *(float4*)(Pst + base + q * 4) = make_float4(P[q*4], P[q*4+1], P[q*4+2], P[q*4+3]);
        *(float4*)(Fst + base + q * 4) = make_float4(h[q*4], h[q*4+1], h[q*4+2], h[q*4+3]);
    }
}

// ---------------- scan phase B ----------------
__global__ __launch_bounds__(256) void scan_b_k(const float* __restrict__ Pst,
                                                float* __restrict__ Fst) {
    const int t = blockIdx.x * 256 + threadIdx.x;
    const int s = t & 15;
    const int d = (t >> 4) & (DI - 1);
    const int b = t >> 12;
    size_t base = ((size_t)(b * DI + d) * NCHUNK) * DS + s;
    float st = 0.f;
#pragma unroll 8
    for (int c = 0; c < NCHUNK; ++c) {
        size_t idx = base + (size_t)c * DS;
        float P = Pst[idx];
        float F = Fst[idx];
        Fst[idx] = st;
        st = fmaf(P, st, F);
    }
}

// ---------------- scan phase C ----------------
__global__ __launch_bounds__(256) void scan_c_k(const float* __restrict__ dt,
                                                const float* __restrict__ xc,
                                                const float* __restrict__ bc,
                                                const float* __restrict__ xz,
                                                const float* __restrict__ A_log,
                                                const float* __restrict__ Dw,
                                                const float* __restrict__ carry,
                                                float* __restrict__ y) {
    __shared__ float BC[LCHUNK][32];
    const int blk   = blockIdx.x;
    const int b     = blk >> 7;
    const int chunk = blk & (NCHUNK - 1);
    const int d     = threadIdx.x;
    const int l0    = chunk * LCHUNK;

    {
        int l = d >> 3, q = d & 7;
        *(float4*)(&BC[l][q * 4]) =
            *(const float4*)(bc + (size_t)(b * LSEQ + l0 + l) * 32 + q * 4);
    }
    float Ads[16];
#pragma unroll
    for (int s = 0; s < 16; ++s) Ads[s] = -expf(A_log[d * DS + s]);
    const float Dd = Dw[d];

    float h[16];
    size_t cbase = ((size_t)(b * DI + d) * NCHUNK + chunk) * DS;
#pragma unroll
    for (int q = 0; q < 4; ++q) {
        float4 c4 = *(const float4*)(carry + cbase + q * 4);
        h[q*4] = c4.x; h[q*4+1] = c4.y; h[q*4+2] = c4.z; h[q*4+3] = c4.w;
    }
    __syncthreads();

    const float* dtp = dt + ((size_t)b * LSEQ + l0) * DI + d;
    const float* xcp = xc + ((size_t)b * LSEQ + l0) * DI + d;
    const float* zp  = xz + ((size_t)b * LSEQ + l0) * NIN + DI + d;
    float* yout      = y  + ((size_t)b * LSEQ + l0) * DI + d;

#pragma unroll 4
    for (int i = 0; i < LCHUNK; ++i) {
        float dtv = dtp[(size_t)i * DI];
        float xcv = xcp[(size_t)i * DI];
        float zv  = zp[(size_t)i * NIN];
        float du  = dtv * xcv;
        float4 b0 = *(float4*)(&BC[i][0]);
        float4 b1 = *(float4*)(&BC[i][4]);
        float4 b2 = *(float4*)(&BC[i][8]);
        float4 b3 = *(float4*)(&BC[i][12]);
        float4 c0 = *(float4*)(&BC[i][16]);
        float4 c1 = *(float4*)(&BC[i][20]);
        float4 c2 = *(float4*)(&BC[i][24]);
        float4 c3 = *(float4*)(&BC[i][28]);
        float bv[16] = {b0.x,b0.y,b0.z,b0.w, b1.x,b1.y,b1.z,b1.w,
                        b2.x,b2.y,b2.z,b2.w, b3.x,b3.y,b3.z,b3.w};
        float cv[16] = {c0.x,c0.y,c0.z,c0.w, c1.x,c1.y,c1.z,c1.w,
                        c2.x,c2.y,c2.z,c2.w, c3.x,c3.y,c3.z,c3.w};
        float yv = 0.f;
#pragma unroll
        for (int s = 0; s < 16; ++s) {
            float a = __expf(dtv * Ads[s]);
            h[s] = fmaf(h[s], a, du * bv[s]);
            yv = fmaf(h[s], cv[s], yv);
        }
        float yf = fmaf(xcv, Dd, yv);
        yout[(size_t)i * DI] = yf * (zv * sigmoid_f(zv));
    }
}

// ---------------- gemm_out: out[b,c,l] = sum_d y[b,l,d] * W_out[d,c] ----------------
__global__ __launch_bounds__(256) void gemm_out_k(const float* __restrict__ y,
                                                  const float* __restrict__ W,
                                                  float* __restrict__ out) {
    __shared__ float As[32][68];
    __shared__ float Bs[32][64];
    const int b  = blockIdx.z;
    const int m0 = blockIdx.y * 64;
    const int n0 = blockIdx.x * 64;
    const int t  = threadIdx.x;
    const int tx = t & 15, ty = t >> 4;

    float acc[4][4];
#pragma unroll
    for (int i = 0; i < 4; ++i)
#pragma unroll
        for (int j = 0; j < 4; ++j) acc[i][j] = 0.f;

    for (int k0 = 0; k0 < DI; k0 += 32) {
#pragma unroll
        for (int i = 0; i < 2; ++i) {
            int slot = t + i * 256;
            int m  = slot >> 3;
            int kq = (slot & 7) << 2;
            float4 v = *(const float4*)(y + ((size_t)b * LSEQ + m0 + m) * DI + k0 + kq);
            As[kq + 0][m] = v.x;
            As[kq + 1][m] = v.y;
            As[kq + 2][m] = v.z;
            As[kq + 3][m] = v.w;
            int kc = slot >> 4;
            int p4 = (slot & 15) << 2;
            *(float4*)(&Bs[kc][p4]) =
                *(const float4*)(W + (size_t)(k0 + kc) * DM + n0 + p4);
        }
        __syncthreads();
#pragma unroll
        for (int k = 0; k < 32; ++k) {
            float a[4], bb[4];
            *(float4*)(a)  = *(float4*)(&As[k][ty * 4]);
            *(float4*)(bb) = *(float4*)(&Bs[k][tx * 4]);
#pragma unroll
            for (int i = 0; i < 4; ++i)
#pragma unroll
                for (int j = 0; j < 4; ++j) acc[i][j] = fmaf(a[i], bb[j], acc[i][j]);
        }
        __syncthreads();
    }
#pragma unroll
    for (int j = 0; j < 4; ++j) {
        int c = n0 + tx * 4 + j;
        float* ocol = out + ((size_t)b * DM + c) * LSEQ + m0;
        *(float4*)(ocol + ty * 4) = make_float4(acc[0][j], acc[1][j], acc[2][j], acc[3][j]);
    }
}

extern "C" void kernel_launch(void* const* d_in, const int* in_sizes, int n_in,
                              void* d_out, int out_size, void* d_ws, size_t ws_size,
                              hipStream_t stream) {
    const float* x      = (const float*)d_in[0];
    const float* W_in   = (const float*)d_in[1];
    const float* conv_w = (const float*)d_in[2];
    const float* conv_b = (const float*)d_in[3];
    const float* W_x    = (const float*)d_in[4];
    const float* W_dt   = (const float*)d_in[5];
    const float* b_dt   = (const float*)d_in[6];
    const float* A_log  = (const float*)d_in[7];
    const float* Dw     = (const float*)d_in[8];
    const float* W_out  = (const float*)d_in[9];
    float* out = (float*)d_out;

    float* ws   = (float*)d_ws;
    float* xz   = ws;                    // B*L*512            = 4,194,304
    float* xc   = xz + 4194304;          // B*L*256            = 2,097,152
    float* bc   = xc + 2097152;          // B*L*32             =   262,144
    float* dtb  = bc + 262144;           // B*L*256            = 2,097,152
    float* Pst  = dtb + 2097152;         // B*DI*NCHUNK*DS     = 1,048,576
    float* Fst  = Pst + 1048576;         // 1,048,576
    float* yb   = Fst + 1048576;         // B*L*DI             = 2,097,152
    float* Bcat = yb + 2097152;          // 256*320            =    81,920

    bcat_k     <<<dim3(256), 320, 0, stream>>>(W_x, W_dt, Bcat);
    gemm_in_k  <<<dim3(8, 64, BSZ), 256, 0, stream>>>(x, W_in, xz);
    conv_silu_k<<<dim3(BSZ * LSEQ / 4), 256, 0, stream>>>(xz, conv_w, conv_b, xc);
    gemm_x2_k  <<<dim3(5, 128), 256, 0, stream>>>(xc, Bcat, b_dt, dtb, bc);
    scan_a_k   <<<dim3(BSZ * NCHUNK), 256, 0, stream>>>(dtb, xc, bc, A_log, Pst, Fst);
    scan_b_k   <<<dim3(BSZ * DI * DS / 256), 256, 0, stream>>>(Pst, Fst);
    scan_c_k   <<<dim3(BSZ * NCHUNK), 256, 0, stream>>>(dtb, xc, bc, xz, A_log, Dw, Fst, yb);
    gemm_out_k <<<dim3(4, 64, BSZ), 256, 0, stream>>>(yb, W_out, out);
}

// Round 6
// 177.432 us; speedup vs baseline: 1.6633x; 1.1111x over previous
//
#include <hip/hip_runtime.h>
#include <math.h>

#define BSZ 2
#define LSEQ 4096
#define DM 256      // d_model
#define DI 256      // d_inner
#define DS 16       // d_state
#define DR 16       // dt_rank
#define NIN 512     // 2*DI
#define NCHUNK 128
#define LCHUNK 32
#define NB2 320     // padded Bcat width (288 real: 256 dt + 32 bc)

typedef __attribute__((ext_vector_type(8))) short short8;
typedef __attribute__((ext_vector_type(4))) float floatx4;

__device__ __forceinline__ float sigmoid_f(float v) {
    return __builtin_amdgcn_rcpf(1.0f + __expf(-v));
}

__device__ __forceinline__ unsigned int bf16_rne(float v) {
    unsigned int u = __float_as_uint(v);
    return (u + 0x7FFFu + ((u >> 16) & 1u)) >> 16;
}

// ---------------- gemm_in (MFMA bf16x3): xz[b,l,n] = sum_c x[b,c,l] * W_in[c,n] ----------------
__global__ __launch_bounds__(256) void gemm_in_k(const float* __restrict__ x,
                                                 const float* __restrict__ W,
                                                 float* __restrict__ xz) {
    __shared__ unsigned short sA[128][40];   // rows 0-63 hi, 64-127 lo; k 0..31 (pad 40)
    __shared__ unsigned short sB[128][40];
    const int b  = blockIdx.z;
    const int m0 = blockIdx.y * 64;
    const int n0 = blockIdx.x * 64;
    const int t  = threadIdx.x;
    const int w    = t >> 6;
    const int lane = t & 63;
    const int kp = t & 15;
    const int g  = t >> 4;

    const int mwb = (w & 1) * 32;
    const int nwb = (w >> 1) * 32;
    const int fr  = lane & 15;
    const int q   = lane >> 4;

    floatx4 acc[2][2];
#pragma unroll
    for (int mi = 0; mi < 2; ++mi)
#pragma unroll
        for (int ni = 0; ni < 2; ++ni) acc[mi][ni] = (floatx4){0.f, 0.f, 0.f, 0.f};

    for (int k0 = 0; k0 < DM; k0 += 32) {
        {
            const float* pa = x + ((size_t)b * DM + k0 + 2 * kp) * LSEQ + m0 + 4 * g;
            float4 fa0 = *(const float4*)(pa);
            float4 fa1 = *(const float4*)(pa + LSEQ);
            const float* a0 = (const float*)&fa0;
            const float* a1 = (const float*)&fa1;
#pragma unroll
            for (int j = 0; j < 4; ++j) {
                int m = 4 * g + j;
                unsigned int h0 = bf16_rne(a0[j]);
                unsigned int h1 = bf16_rne(a1[j]);
                float r0 = a0[j] - __uint_as_float(h0 << 16);
                float r1 = a1[j] - __uint_as_float(h1 << 16);
                unsigned int l0 = bf16_rne(r0);
                unsigned int l1 = bf16_rne(r1);
                *(unsigned int*)&sA[m][2 * kp]      = h0 | (h1 << 16);
                *(unsigned int*)&sA[64 + m][2 * kp] = l0 | (l1 << 16);
            }
            const float* pb = W + (size_t)(k0 + 2 * kp) * NIN + n0 + 4 * g;
            float4 fb0 = *(const float4*)(pb);
            float4 fb1 = *(const float4*)(pb + NIN);
            const float* b0 = (const float*)&fb0;
            const float* b1 = (const float*)&fb1;
#pragma unroll
            for (int j = 0; j < 4; ++j) {
                int n = 4 * g + j;
                unsigned int h0 = bf16_rne(b0[j]);
                unsigned int h1 = bf16_rne(b1[j]);
                float r0 = b0[j] - __uint_as_float(h0 << 16);
                float r1 = b1[j] - __uint_as_float(h1 << 16);
                unsigned int l0 = bf16_rne(r0);
                unsigned int l1 = bf16_rne(r1);
                *(unsigned int*)&sB[n][2 * kp]      = h0 | (h1 << 16);
                *(unsigned int*)&sB[64 + n][2 * kp] = l0 | (l1 << 16);
            }
        }
        __syncthreads();

        short8 ah[2], al[2], bh[2], bl[2];
#pragma unroll
        for (int mi = 0; mi < 2; ++mi) {
            int mr = mwb + mi * 16 + fr;
            ah[mi] = *(const short8*)&sA[mr][q * 8];
            al[mi] = *(const short8*)&sA[64 + mr][q * 8];
        }
#pragma unroll
        for (int ni = 0; ni < 2; ++ni) {
            int nr = nwb + ni * 16 + fr;
            bh[ni] = *(const short8*)&sB[nr][q * 8];
            bl[ni] = *(const short8*)&sB[64 + nr][q * 8];
        }
#pragma unroll
        for (int mi = 0; mi < 2; ++mi)
#pragma unroll
            for (int ni = 0; ni < 2; ++ni) {
                acc[mi][ni] = __builtin_amdgcn_mfma_f32_16x16x32_bf16(ah[mi], bh[ni], acc[mi][ni], 0, 0, 0);
                acc[mi][ni] = __builtin_amdgcn_mfma_f32_16x16x32_bf16(ah[mi], bl[ni], acc[mi][ni], 0, 0, 0);
                acc[mi][ni] = __builtin_amdgcn_mfma_f32_16x16x32_bf16(al[mi], bh[ni], acc[mi][ni], 0, 0, 0);
            }
        __syncthreads();
    }

#pragma unroll
    for (int mi = 0; mi < 2; ++mi)
#pragma unroll
        for (int ni = 0; ni < 2; ++ni) {
#pragma unroll
            for (int r = 0; r < 4; ++r) {
                int m = m0 + mwb + mi * 16 + q * 4 + r;
                int n = n0 + nwb + ni * 16 + fr;
                xz[((size_t)b * LSEQ + m) * NIN + n] = acc[mi][ni][r];
            }
        }
}

// ---------------- conv + silu: xc[b,l,d] ----------------
__global__ __launch_bounds__(256) void conv_silu_k(const float* __restrict__ xz,
                                                   const float* __restrict__ conv_w,
                                                   const float* __restrict__ conv_b,
                                                   float* __restrict__ xc) {
    const int t   = threadIdx.x;
    const int idx = blockIdx.x * 4 + (t >> 6);
    const int b   = idx >> 12;
    const int l   = idx & (LSEQ - 1);
    const int dq  = (t & 63) << 2;

    float4 cw0 = *(const float4*)(conv_w + (dq + 0) * 4);
    float4 cw1 = *(const float4*)(conv_w + (dq + 1) * 4);
    float4 cw2 = *(const float4*)(conv_w + (dq + 2) * 4);
    float4 cw3 = *(const float4*)(conv_w + (dq + 3) * 4);
    const float* cwp0 = (const float*)&cw0;
    const float* cwp1 = (const float*)&cw1;
    const float* cwp2 = (const float*)&cw2;
    const float* cwp3 = (const float*)&cw3;

    float4 acc = *(const float4*)(conv_b + dq);
#pragma unroll
    for (int k = 0; k < 4; ++k) {
        int ls = l - 3 + k;
        if (ls >= 0) {
            float4 v = *(const float4*)(xz + ((size_t)b * LSEQ + ls) * NIN + dq);
            acc.x = fmaf(v.x, cwp0[k], acc.x);
            acc.y = fmaf(v.y, cwp1[k], acc.y);
            acc.z = fmaf(v.z, cwp2[k], acc.z);
            acc.w = fmaf(v.w, cwp3[k], acc.w);
        }
    }
    acc.x *= sigmoid_f(acc.x);
    acc.y *= sigmoid_f(acc.y);
    acc.z *= sigmoid_f(acc.z);
    acc.w *= sigmoid_f(acc.w);
    *(float4*)(xc + (size_t)idx * DI + dq) = acc;
}

// ---------------- bcat ----------------
__global__ __launch_bounds__(320) void bcat_k(const float* __restrict__ W_x,
                                              const float* __restrict__ W_dt,
                                              float* __restrict__ Bcat) {
    __shared__ float wr[16];
    const int c = blockIdx.x;
    const int t = threadIdx.x;
    if (t < 16) wr[t] = W_x[(size_t)c * 48 + t];
    __syncthreads();
    if (t < 256) {
        float acc = 0.f;
#pragma unroll
        for (int r = 0; r < 16; ++r) acc = fmaf(wr[r], W_dt[r * DI + t], acc);
        Bcat[(size_t)c * NB2 + t] = acc;
    } else if (t < 288) {
        Bcat[(size_t)c * NB2 + t] = W_x[(size_t)c * 48 + 16 + (t - 256)];
    } else {
        Bcat[(size_t)c * NB2 + t] = 0.f;
    }
}

// ---------------- gemm_x2 (MFMA bf16x3): [dt | bc] = xc @ Bcat ----------------
__global__ __launch_bounds__(256) void gemm_x2_k(const float* __restrict__ xc,
                                                 const float* __restrict__ Bcat,
                                                 const float* __restrict__ b_dt,
                                                 float* __restrict__ dt,
                                                 float* __restrict__ bc) {
    __shared__ unsigned short sA[128][40];
    __shared__ unsigned short sB[128][40];
    const int m0 = blockIdx.y * 64;
    const int n0 = blockIdx.x * 64;
    const int t  = threadIdx.x;
    const int w    = t >> 6;
    const int lane = t & 63;
    const int kp = t & 15;
    const int g  = t >> 4;
    const int mwb = (w & 1) * 32;
    const int nwb = (w >> 1) * 32;
    const int fr  = lane & 15;
    const int q   = lane >> 4;

    floatx4 acc[2][2];
#pragma unroll
    for (int mi = 0; mi < 2; ++mi)
#pragma unroll
        for (int ni = 0; ni < 2; ++ni) acc[mi][ni] = (floatx4){0.f, 0.f, 0.f, 0.f};

    for (int k0 = 0; k0 < DI; k0 += 32) {
        {
            // A: xc k-contiguous. row = t>>2 (0..63), kq8 = (t&3)*8
            const int row = t >> 2;
            const int kq8 = (t & 3) * 8;
            const float* pa = xc + (size_t)(m0 + row) * DI + k0 + kq8;
            float v[8];
            *(float4*)(v)     = *(const float4*)(pa);
            *(float4*)(v + 4) = *(const float4*)(pa + 4);
            short8 hi, lo;
#pragma unroll
            for (int j = 0; j < 8; ++j) {
                unsigned int h = bf16_rne(v[j]);
                float r = v[j] - __uint_as_float(h << 16);
                hi[j] = (short)h;
                lo[j] = (short)bf16_rne(r);
            }
            *(short8*)&sA[row][kq8]      = hi;
            *(short8*)&sA[64 + row][kq8] = lo;

            // B: Bcat n-contiguous
            const float* pb = Bcat + (size_t)(k0 + 2 * kp) * NB2 + n0 + 4 * g;
            float4 fb0 = *(const float4*)(pb);
            float4 fb1 = *(const float4*)(pb + NB2);
            const float* b0 = (const float*)&fb0;
            const float* b1 = (const float*)&fb1;
#pragma unroll
            for (int j = 0; j < 4; ++j) {
                int n = 4 * g + j;
                unsigned int h0 = bf16_rne(b0[j]);
                unsigned int h1 = bf16_rne(b1[j]);
                float r0 = b0[j] - __uint_as_float(h0 << 16);
                float r1 = b1[j] - __uint_as_float(h1 << 16);
                unsigned int l0 = bf16_rne(r0);
                unsigned int l1 = bf16_rne(r1);
                *(unsigned int*)&sB[n][2 * kp]      = h0 | (h1 << 16);
                *(unsigned int*)&sB[64 + n][2 * kp] = l0 | (l1 << 16);
            }
        }
        __syncthreads();

        short8 ah[2], al[2], bh[2], bl[2];
#pragma unroll
        for (int mi = 0; mi < 2; ++mi) {
            int mr = mwb + mi * 16 + fr;
            ah[mi] = *(const short8*)&sA[mr][q * 8];
            al[mi] = *(const short8*)&sA[64 + mr][q * 8];
        }
#pragma unroll
        for (int ni = 0; ni < 2; ++ni) {
            int nr = nwb + ni * 16 + fr;
            bh[ni] = *(const short8*)&sB[nr][q * 8];
            bl[ni] = *(const short8*)&sB[64 + nr][q * 8];
        }
#pragma unroll
        for (int mi = 0; mi < 2; ++mi)
#pragma unroll
            for (int ni = 0; ni < 2; ++ni) {
                acc[mi][ni] = __builtin_amdgcn_mfma_f32_16x16x32_bf16(ah[mi], bh[ni], acc[mi][ni], 0, 0, 0);
                acc[mi][ni] = __builtin_amdgcn_mfma_f32_16x16x32_bf16(ah[mi], bl[ni], acc[mi][ni], 0, 0, 0);
                acc[mi][ni] = __builtin_amdgcn_mfma_f32_16x16x32_bf16(al[mi], bh[ni], acc[mi][ni], 0, 0, 0);
            }
        __syncthreads();
    }

#pragma unroll
    for (int mi = 0; mi < 2; ++mi)
#pragma unroll
        for (int ni = 0; ni < 2; ++ni) {
            int n = n0 + nwb + ni * 16 + fr;
            if (n < 256) {
                float bd = b_dt[n];
#pragma unroll
                for (int r = 0; r < 4; ++r) {
                    int m = m0 + mwb + mi * 16 + q * 4 + r;
                    float a2 = acc[mi][ni][r] + bd;
                    float sp = fmaxf(a2, 0.f) + __logf(1.f + __expf(-fabsf(a2)));
                    dt[(size_t)m * DI + n] = sp;
                }
            } else if (n < 288) {
#pragma unroll
                for (int r = 0; r < 4; ++r) {
                    int m = m0 + mwb + mi * 16 + q * 4 + r;
                    bc[(size_t)m * 32 + (n - 256)] = acc[mi][ni][r];
                }
            }
        }
}

// ---------------- scan phase A ----------------
__global__ __launch_bounds__(256) void scan_a_k(const float* __restrict__ dt,
                                                const float* __restrict__ xc,
                                                const float* __restrict__ bc,
                                                const float* __restrict__ A_log,
                                                float* __restrict__ Pst,
                                                float* __restrict__ Fst) {
    __shared__ float Bl[LCHUNK][16];
    const int blk   = blockIdx.x;
    const int b     = blk >> 7;
    const int chunk = blk & (NCHUNK - 1);
    const int d     = threadIdx.x;
    const int l0    = chunk * LCHUNK;

    if (d < LCHUNK * 4) {
        int l = d >> 2, q = d & 3;
        *(float4*)(&Bl[l][q * 4]) =
            *(const float4*)(bc + (size_t)(b * LSEQ + l0 + l) * 32 + q * 4);
    }
    float Ads[16];
#pragma unroll
    for (int s = 0; s < 16; ++s) Ads[s] = -expf(A_log[d * DS + s]);
    __syncthreads();

    float h[16], P[16];
#pragma unroll
    for (int s = 0; s < 16; ++s) { h[s] = 0.f; P[s] = 1.f; }

    const float* dtp = dt + ((size_t)b * LSEQ + l0) * DI + d;
    const float* xcp = xc + ((size_t)b * LSEQ + l0) * DI + d;

#pragma unroll 4
    for (int i = 0; i < LCHUNK; ++i) {
        float dtv = dtp[(size_t)i * DI];
        float xcv = xcp[(size_t)i * DI];
        float du  = dtv * xcv;
        float4 b0 = *(float4*)(&Bl[i][0]);
        float4 b1 = *(float4*)(&Bl[i][4]);
        float4 b2 = *(float4*)(&Bl[i][8]);
        float4 b3 = *(float4*)(&Bl[i][12]);
        float bv[16] = {b0.x,b0.y,b0.z,b0.w, b1.x,b1.y,b1.z,b1.w,
                        b2.x,b2.y,b2.z,b2.w, b3.x,b3.y,b3.z,b3.w};
#pragma unroll
        for (int s = 0; s < 16; ++s) {
            float a = __expf(dtv * Ads[s]);
            h[s] = fmaf(h[s], a, du * bv[s]);
            P[s] *= a;
        }
    }
    size_t base = ((size_t)(b * DI + d) * NCHUNK + chunk) * DS;
#pragma unroll
    for (int q = 0; q < 4; ++q) {
        *(float4*)(Pst + base + q * 4) = make_float4(P[q*4], P[q*4+1], P[q*4+2], P[q*4+3]);
        *(float4*)(Fst + base + q * 4) = make_float4(h[q*4], h[q*4+1], h[q*4+2], h[q*4+3]);
    }
}

// ---------------- scan phase B ----------------
__global__ __launch_bounds__(256) void scan_b_k(const float* __restrict__ Pst,
                                                float* __restrict__ Fst) {
    const int t = blockIdx.x * 256 + threadIdx.x;
    const int s = t & 15;
    const int d = (t >> 4) & (DI - 1);
    const int b = t >> 12;
    size_t base = ((size_t)(b * DI + d) * NCHUNK) * DS + s;
    float st = 0.f;
#pragma unroll 8
    for (int c = 0; c < NCHUNK; ++c) {
        size_t idx = base + (size_t)c * DS;
        float P = Pst[idx];
        float F = Fst[idx];
        Fst[idx] = st;
        st = fmaf(P, st, F);
    }
}

// ---------------- scan phase C ----------------
__global__ __launch_bounds__(256) void scan_c_k(const float* __restrict__ dt,
                                                const float* __restrict__ xc,
                                                const float* __restrict__ bc,
                                                const float* __restrict__ xz,
                                                const float* __restrict__ A_log,
                                                const float* __restrict__ Dw,
                                                const float* __restrict__ carry,
                                                float* __restrict__ y) {
    __shared__ float BC[LCHUNK][32];
    const int blk   = blockIdx.x;
    const int b     = blk >> 7;
    const int chunk = blk & (NCHUNK - 1);
    const int d     = threadIdx.x;
    const int l0    = chunk * LCHUNK;

    {
        int l = d >> 3, q = d & 7;
        *(float4*)(&BC[l][q * 4]) =
            *(const float4*)(bc + (size_t)(b * LSEQ + l0 + l) * 32 + q * 4);
    }
    float Ads[16];
#pragma unroll
    for (int s = 0; s < 16; ++s) Ads[s] = -expf(A_log[d * DS + s]);
    const float Dd = Dw[d];

    float h[16];
    size_t cbase = ((size_t)(b * DI + d) * NCHUNK + chunk) * DS;
#pragma unroll
    for (int q = 0; q < 4; ++q) {
        float4 c4 = *(const float4*)(carry + cbase + q * 4);
        h[q*4] = c4.x; h[q*4+1] = c4.y; h[q*4+2] = c4.z; h[q*4+3] = c4.w;
    }
    __syncthreads();

    const float* dtp = dt + ((size_t)b * LSEQ + l0) * DI + d;
    const float* xcp = xc + ((size_t)b * LSEQ + l0) * DI + d;
    const float* zp  = xz + ((size_t)b * LSEQ + l0) * NIN + DI + d;
    float* yout      = y  + ((size_t)b * LSEQ + l0) * DI + d;

#pragma unroll 4
    for (int i = 0; i < LCHUNK; ++i) {
        float dtv = dtp[(size_t)i * DI];
        float xcv = xcp[(size_t)i * DI];
        float zv  = zp[(size_t)i * NIN];
        float du  = dtv * xcv;
        float4 b0 = *(float4*)(&BC[i][0]);
        float4 b1 = *(float4*)(&BC[i][4]);
        float4 b2 = *(float4*)(&BC[i][8]);
        float4 b3 = *(float4*)(&BC[i][12]);
        float4 c0 = *(float4*)(&BC[i][16]);
        float4 c1 = *(float4*)(&BC[i][20]);
        float4 c2 = *(float4*)(&BC[i][24]);
        float4 c3 = *(float4*)(&BC[i][28]);
        float bv[16] = {b0.x,b0.y,b0.z,b0.w, b1.x,b1.y,b1.z,b1.w,
                        b2.x,b2.y,b2.z,b2.w, b3.x,b3.y,b3.z,b3.w};
        float cv[16] = {c0.x,c0.y,c0.z,c0.w, c1.x,c1.y,c1.z,c1.w,
                        c2.x,c2.y,c2.z,c2.w, c3.x,c3.y,c3.z,c3.w};
        float yv = 0.f;
#pragma unroll
        for (int s = 0; s < 16; ++s) {
            float a = __expf(dtv * Ads[s]);
            h[s] = fmaf(h[s], a, du * bv[s]);
            yv = fmaf(h[s], cv[s], yv);
        }
        float yf = fmaf(xcv, Dd, yv);
        yout[(size_t)i * DI] = yf * (zv * sigmoid_f(zv));
    }
}

// ---------------- gemm_out (MFMA bf16x3): out[b,c,l] = sum_d y[b,l,d] * W_out[d,c] ----------------
__global__ __launch_bounds__(256) void gemm_out_k(const float* __restrict__ y,
                                                  const float* __restrict__ W,
                                                  float* __restrict__ out) {
    __shared__ unsigned short sA[128][40];
    __shared__ unsigned short sB[128][40];
    const int b  = blockIdx.z;
    const int m0 = blockIdx.y * 64;    // l
    const int n0 = blockIdx.x * 64;    // c
    const int t  = threadIdx.x;
    const int w    = t >> 6;
    const int lane = t & 63;
    const int kp = t & 15;
    const int g  = t >> 4;
    const int mwb = (w & 1) * 32;
    const int nwb = (w >> 1) * 32;
    const int fr  = lane & 15;
    const int q   = lane >> 4;

    floatx4 acc[2][2];
#pragma unroll
    for (int mi = 0; mi < 2; ++mi)
#pragma unroll
        for (int ni = 0; ni < 2; ++ni) acc[mi][ni] = (floatx4){0.f, 0.f, 0.f, 0.f};

    for (int k0 = 0; k0 < DI; k0 += 32) {
        {
            // A: y k-contiguous
            const int row = t >> 2;
            const int kq8 = (t & 3) * 8;
            const float* pa = y + ((size_t)b * LSEQ + m0 + row) * DI + k0 + kq8;
            float v[8];
            *(float4*)(v)     = *(const float4*)(pa);
            *(float4*)(v + 4) = *(const float4*)(pa + 4);
            short8 hi, lo;
#pragma unroll
            for (int j = 0; j < 8; ++j) {
                unsigned int h = bf16_rne(v[j]);
                float r = v[j] - __uint_as_float(h << 16);
                hi[j] = (short)h;
                lo[j] = (short)bf16_rne(r);
            }
            *(short8*)&sA[row][kq8]      = hi;
            *(short8*)&sA[64 + row][kq8] = lo;

            // B: W_out n-contiguous
            const float* pb = W + (size_t)(k0 + 2 * kp) * DM + n0 + 4 * g;
            float4 fb0 = *(const float4*)(pb);
            float4 fb1 = *(const float4*)(pb + DM);
            const float* b0 = (const float*)&fb0;
            const float* b1 = (const float*)&fb1;
#pragma unroll
            for (int j = 0; j < 4; ++j) {
                int n = 4 * g + j;
                unsigned int h0 = bf16_rne(b0[j]);
                unsigned int h1 = bf16_rne(b1[j]);
                float r0 = b0[j] - __uint_as_float(h0 << 16);
                float r1 = b1[j] - __uint_as_float(h1 << 16);
                unsigned int l0 = bf16_rne(r0);
                unsigned int l1 = bf16_rne(r1);
                *(unsigned int*)&sB[n][2 * kp]      = h0 | (h1 << 16);
                *(unsigned int*)&sB[64 + n][2 * kp] = l0 | (l1 << 16);
            }
        }
        __syncthreads();

        short8 ah[2], al[2], bh[2], bl[2];
#pragma unroll
        for (int mi = 0; mi < 2; ++mi) {
            int mr = mwb + mi * 16 + fr;
            ah[mi] = *(const short8*)&sA[mr][q * 8];
            al[mi] = *(const short8*)&sA[64 + mr][q * 8];
        }
#pragma unroll
        for (int ni = 0; ni < 2; ++ni) {
            int nr = nwb + ni * 16 + fr;
            bh[ni] = *(const short8*)&sB[nr][q * 8];
            bl[ni] = *(const short8*)&sB[64 + nr][q * 8];
        }
#pragma unroll
        for (int mi = 0; mi < 2; ++mi)
#pragma unroll
            for (int ni = 0; ni < 2; ++ni) {
                acc[mi][ni] = __builtin_amdgcn_mfma_f32_16x16x32_bf16(ah[mi], bh[ni], acc[mi][ni], 0, 0, 0);
                acc[mi][ni] = __builtin_amdgcn_mfma_f32_16x16x32_bf16(ah[mi], bl[ni], acc[mi][ni], 0, 0, 0);
                acc[mi][ni] = __builtin_amdgcn_mfma_f32_16x16x32_bf16(al[mi], bh[ni], acc[mi][ni], 0, 0, 0);
            }
        __syncthreads();
    }

    // out[(b*DM + c)*LSEQ + l]: lane's reg-quad = 4 consecutive l -> float4 store
#pragma unroll
    for (int mi = 0; mi < 2; ++mi)
#pragma unroll
        for (int ni = 0; ni < 2; ++ni) {
            int c = n0 + nwb + ni * 16 + fr;
            float* op = out + ((size_t)b * DM + c) * LSEQ + m0 + mwb + mi * 16 + q * 4;
            *(float4*)op = make_float4(acc[mi][ni][0], acc[mi][ni][1],
                                       acc[mi][ni][2], acc[mi][ni][3]);
        }
}

extern "C" void kernel_launch(void* const* d_in, const int* in_sizes, int n_in,
                              void* d_out, int out_size, void* d_ws, size_t ws_size,
                              hipStream_t stream) {
    const float* x      = (const float*)d_in[0];
    const float* W_in   = (const float*)d_in[1];
    const float* conv_w = (const float*)d_in[2];
    const float* conv_b = (const float*)d_in[3];
    const float* W_x    = (const float*)d_in[4];
    const float* W_dt   = (const float*)d_in[5];
    const float* b_dt   = (const float*)d_in[6];
    const float* A_log  = (const float*)d_in[7];
    const float* Dw     = (const float*)d_in[8];
    const float* W_out  = (const float*)d_in[9];
    float* out = (float*)d_out;

    float* ws   = (float*)d_ws;
    float* xz   = ws;                    // B*L*512            = 4,194,304
    float* xc   = xz + 4194304;          // B*L*256            = 2,097,152
    float* bc   = xc + 2097152;          // B*L*32             =   262,144
    float* dtb  = bc + 262144;           // B*L*256            = 2,097,152
    float* Pst  = dtb + 2097152;         // B*DI*NCHUNK*DS     = 1,048,576
    float* Fst  = Pst + 1048576;         // 1,048,576
    float* yb   = Fst + 1048576;         // B*L*DI             = 2,097,152
    float* Bcat = yb + 2097152;          // 256*320            =    81,920

    bcat_k     <<<dim3(256), 320, 0, stream>>>(W_x, W_dt, Bcat);
    gemm_in_k  <<<dim3(8, 64, BSZ), 256, 0, stream>>>(x, W_in, xz);
    conv_silu_k<<<dim3(BSZ * LSEQ / 4), 256, 0, stream>>>(xz, conv_w, conv_b, xc);
    gemm_x2_k  <<<dim3(5, 128), 256, 0, stream>>>(xc, Bcat, b_dt, dtb, bc);
    scan_a_k   <<<dim3(BSZ * NCHUNK), 256, 0, stream>>>(dtb, xc, bc, A_log, Pst, Fst);
    scan_b_k   <<<dim3(BSZ * DI * DS / 256), 256, 0, stream>>>(Pst, Fst);
    scan_c_k   <<<dim3(BSZ * NCHUNK), 256, 0, stream>>>(dtb, xc, bc, xz, A_log, Dw, Fst, yb);
    gemm_out_k <<<dim3(4, 64, BSZ), 256, 0, stream>>>(yb, W_out, out);
}

// Round 7
// 174.752 us; speedup vs baseline: 1.6888x; 1.0153x over previous
//
#include <hip/hip_runtime.h>
#include <math.h>

#define BSZ 2
#define LSEQ 4096
#define DM 256      // d_model
#define DI 256      // d_inner
#define DS 16       // d_state
#define DR 16       // dt_rank
#define NIN 512     // 2*DI
#define NCHUNK 256
#define LCHUNK 16
#define NB2 320     // padded Bcat width (288 real: 256 dt + 32 bc)

typedef __attribute__((ext_vector_type(8))) short short8;
typedef __attribute__((ext_vector_type(4))) float floatx4;

__device__ __forceinline__ float sigmoid_f(float v) {
    return __builtin_amdgcn_rcpf(1.0f + __expf(-v));
}

__device__ __forceinline__ unsigned int bf16_rne(float v) {
    unsigned int u = __float_as_uint(v);
    return (u + 0x7FFFu + ((u >> 16) & 1u)) >> 16;
}

// ---------------- wsplit: transpose+split W_in, W_out into bf16 hi/lo ----------------
// WinT[n][k] (512x256), WoutT[n][k] (256x256)
__global__ __launch_bounds__(512) void wsplit_k(const float* __restrict__ W_in,
                                                const float* __restrict__ W_out,
                                                unsigned short* __restrict__ WinT_hi,
                                                unsigned short* __restrict__ WinT_lo,
                                                unsigned short* __restrict__ WoutT_hi,
                                                unsigned short* __restrict__ WoutT_lo) {
    const int k = blockIdx.x;          // 0..255
    const int t = threadIdx.x;         // 0..511
    {
        float v = W_in[(size_t)k * NIN + t];
        unsigned int h = bf16_rne(v);
        float r = v - __uint_as_float(h << 16);
        WinT_hi[(size_t)t * DM + k] = (unsigned short)h;
        WinT_lo[(size_t)t * DM + k] = (unsigned short)bf16_rne(r);
    }
    if (t < DM) {
        float v = W_out[(size_t)k * DM + t];
        unsigned int h = bf16_rne(v);
        float r = v - __uint_as_float(h << 16);
        WoutT_hi[(size_t)t * DM + k] = (unsigned short)h;
        WoutT_lo[(size_t)t * DM + k] = (unsigned short)bf16_rne(r);
    }
}

// ---------------- bcat: BcatT[n][k] split bf16; n<256: W_x[:,:16]@W_dt, 256-287: B/C cols, 288+: 0 ----------------
__global__ __launch_bounds__(320) void bcat_k(const float* __restrict__ W_x,
                                              const float* __restrict__ W_dt,
                                              unsigned short* __restrict__ BcatT_hi,
                                              unsigned short* __restrict__ BcatT_lo) {
    __shared__ float wr[16];
    const int c = blockIdx.x;          // k index 0..255
    const int t = threadIdx.x;         // n index 0..319
    if (t < 16) wr[t] = W_x[(size_t)c * 48 + t];
    __syncthreads();
    float v;
    if (t < 256) {
        float acc = 0.f;
#pragma unroll
        for (int r = 0; r < 16; ++r) acc = fmaf(wr[r], W_dt[r * DI + t], acc);
        v = acc;
    } else if (t < 288) {
        v = W_x[(size_t)c * 48 + 16 + (t - 256)];
    } else {
        v = 0.f;
    }
    unsigned int h = bf16_rne(v);
    float r = v - __uint_as_float(h << 16);
    BcatT_hi[(size_t)t * DM + c] = (unsigned short)h;
    BcatT_lo[(size_t)t * DM + c] = (unsigned short)bf16_rne(r);
}

// ---------------- gemm_in (MFMA bf16x3): xz[b,l,n] = sum_c x[b,c,l] * W_in[c,n] ----------------
__global__ __launch_bounds__(256) void gemm_in_k(const float* __restrict__ x,
                                                 const unsigned short* __restrict__ WT_hi,
                                                 const unsigned short* __restrict__ WT_lo,
                                                 float* __restrict__ xz) {
    __shared__ unsigned short sA[128][40];   // rows 0-63 hi, 64-127 lo; k 0..31 (pad 40)
    __shared__ unsigned short sB[128][40];
    const int b  = blockIdx.z;
    const int m0 = blockIdx.y * 64;
    const int n0 = blockIdx.x * 64;
    const int t  = threadIdx.x;
    const int w    = t >> 6;
    const int lane = t & 63;
    const int kp = t & 15;
    const int g  = t >> 4;

    const int mwb = (w & 1) * 32;
    const int nwb = (w >> 1) * 32;
    const int fr  = lane & 15;
    const int q   = lane >> 4;

    const int brow = t >> 2;          // 0..63 (n rel)
    const int bkq8 = (t & 3) * 8;     // 0,8,16,24

    floatx4 acc[2][2];
#pragma unroll
    for (int mi = 0; mi < 2; ++mi)
#pragma unroll
        for (int ni = 0; ni < 2; ++ni) acc[mi][ni] = (floatx4){0.f, 0.f, 0.f, 0.f};

    for (int k0 = 0; k0 < DM; k0 += 32) {
        {
            // A: x [k][m], convert+split in-kernel
            const float* pa = x + ((size_t)b * DM + k0 + 2 * kp) * LSEQ + m0 + 4 * g;
            float4 fa0 = *(const float4*)(pa);
            float4 fa1 = *(const float4*)(pa + LSEQ);
            const float* a0 = (const float*)&fa0;
            const float* a1 = (const float*)&fa1;
#pragma unroll
            for (int j = 0; j < 4; ++j) {
                int m = 4 * g + j;
                unsigned int h0 = bf16_rne(a0[j]);
                unsigned int h1 = bf16_rne(a1[j]);
                float r0 = a0[j] - __uint_as_float(h0 << 16);
                float r1 = a1[j] - __uint_as_float(h1 << 16);
                unsigned int l0 = bf16_rne(r0);
                unsigned int l1 = bf16_rne(r1);
                *(unsigned int*)&sA[m][2 * kp]      = h0 | (h1 << 16);
                *(unsigned int*)&sA[64 + m][2 * kp] = l0 | (l1 << 16);
            }
            // B: pre-split transposed weights — straight copies
            const size_t boff = (size_t)(n0 + brow) * DM + k0 + bkq8;
            *(short8*)&sB[brow][bkq8]      = *(const short8*)(WT_hi + boff);
            *(short8*)&sB[64 + brow][bkq8] = *(const short8*)(WT_lo + boff);
        }
        __syncthreads();

        short8 ah[2], al[2], bh[2], bl[2];
#pragma unroll
        for (int mi = 0; mi < 2; ++mi) {
            int mr = mwb + mi * 16 + fr;
            ah[mi] = *(const short8*)&sA[mr][q * 8];
            al[mi] = *(const short8*)&sA[64 + mr][q * 8];
        }
#pragma unroll
        for (int ni = 0; ni < 2; ++ni) {
            int nr = nwb + ni * 16 + fr;
            bh[ni] = *(const short8*)&sB[nr][q * 8];
            bl[ni] = *(const short8*)&sB[64 + nr][q * 8];
        }
#pragma unroll
        for (int mi = 0; mi < 2; ++mi)
#pragma unroll
            for (int ni = 0; ni < 2; ++ni) {
                acc[mi][ni] = __builtin_amdgcn_mfma_f32_16x16x32_bf16(ah[mi], bh[ni], acc[mi][ni], 0, 0, 0);
                acc[mi][ni] = __builtin_amdgcn_mfma_f32_16x16x32_bf16(ah[mi], bl[ni], acc[mi][ni], 0, 0, 0);
                acc[mi][ni] = __builtin_amdgcn_mfma_f32_16x16x32_bf16(al[mi], bh[ni], acc[mi][ni], 0, 0, 0);
            }
        __syncthreads();
    }

#pragma unroll
    for (int mi = 0; mi < 2; ++mi)
#pragma unroll
        for (int ni = 0; ni < 2; ++ni) {
#pragma unroll
            for (int r = 0; r < 4; ++r) {
                int m = m0 + mwb + mi * 16 + q * 4 + r;
                int n = n0 + nwb + ni * 16 + fr;
                xz[((size_t)b * LSEQ + m) * NIN + n] = acc[mi][ni][r];
            }
        }
}

// ---------------- conv + silu: xc[b,l,d] ----------------
__global__ __launch_bounds__(256) void conv_silu_k(const float* __restrict__ xz,
                                                   const float* __restrict__ conv_w,
                                                   const float* __restrict__ conv_b,
                                                   float* __restrict__ xc) {
    const int t   = threadIdx.x;
    const int idx = blockIdx.x * 4 + (t >> 6);
    const int b   = idx >> 12;
    const int l   = idx & (LSEQ - 1);
    const int dq  = (t & 63) << 2;

    float4 cw0 = *(const float4*)(conv_w + (dq + 0) * 4);
    float4 cw1 = *(const float4*)(conv_w + (dq + 1) * 4);
    float4 cw2 = *(const float4*)(conv_w + (dq + 2) * 4);
    float4 cw3 = *(const float4*)(conv_w + (dq + 3) * 4);
    const float* cwp0 = (const float*)&cw0;
    const float* cwp1 = (const float*)&cw1;
    const float* cwp2 = (const float*)&cw2;
    const float* cwp3 = (const float*)&cw3;

    float4 acc = *(const float4*)(conv_b + dq);
#pragma unroll
    for (int k = 0; k < 4; ++k) {
        int ls = l - 3 + k;
        if (ls >= 0) {
            float4 v = *(const float4*)(xz + ((size_t)b * LSEQ + ls) * NIN + dq);
            acc.x = fmaf(v.x, cwp0[k], acc.x);
            acc.y = fmaf(v.y, cwp1[k], acc.y);
            acc.z = fmaf(v.z, cwp2[k], acc.z);
            acc.w = fmaf(v.w, cwp3[k], acc.w);
        }
    }
    acc.x *= sigmoid_f(acc.x);
    acc.y *= sigmoid_f(acc.y);
    acc.z *= sigmoid_f(acc.z);
    acc.w *= sigmoid_f(acc.w);
    *(float4*)(xc + (size_t)idx * DI + dq) = acc;
}

// ---------------- gemm_x2 (MFMA bf16x3): [dt | bc] = xc @ Bcat ----------------
__global__ __launch_bounds__(256) void gemm_x2_k(const float* __restrict__ xc,
                                                 const unsigned short* __restrict__ BT_hi,
                                                 const unsigned short* __restrict__ BT_lo,
                                                 const float* __restrict__ b_dt,
                                                 float* __restrict__ dt,
                                                 float* __restrict__ bc) {
    __shared__ unsigned short sA[128][40];
    __shared__ unsigned short sB[128][40];
    const int m0 = blockIdx.y * 64;
    const int n0 = blockIdx.x * 64;
    const int t  = threadIdx.x;
    const int w    = t >> 6;
    const int lane = t & 63;
    const int mwb = (w & 1) * 32;
    const int nwb = (w >> 1) * 32;
    const int fr  = lane & 15;
    const int q   = lane >> 4;

    const int row = t >> 2;
    const int kq8 = (t & 3) * 8;

    floatx4 acc[2][2];
#pragma unroll
    for (int mi = 0; mi < 2; ++mi)
#pragma unroll
        for (int ni = 0; ni < 2; ++ni) acc[mi][ni] = (floatx4){0.f, 0.f, 0.f, 0.f};

    for (int k0 = 0; k0 < DI; k0 += 32) {
        {
            // A: xc k-contiguous, convert+split
            const float* pa = xc + (size_t)(m0 + row) * DI + k0 + kq8;
            float v[8];
            *(float4*)(v)     = *(const float4*)(pa);
            *(float4*)(v + 4) = *(const float4*)(pa + 4);
            short8 hi, lo;
#pragma unroll
            for (int j = 0; j < 8; ++j) {
                unsigned int h = bf16_rne(v[j]);
                float r = v[j] - __uint_as_float(h << 16);
                hi[j] = (short)h;
                lo[j] = (short)bf16_rne(r);
            }
            *(short8*)&sA[row][kq8]      = hi;
            *(short8*)&sA[64 + row][kq8] = lo;

            // B: pre-split transposed Bcat
            const size_t boff = (size_t)(n0 + row) * DM + k0 + kq8;
            *(short8*)&sB[row][kq8]      = *(const short8*)(BT_hi + boff);
            *(short8*)&sB[64 + row][kq8] = *(const short8*)(BT_lo + boff);
        }
        __syncthreads();

        short8 ah[2], al[2], bh[2], bl[2];
#pragma unroll
        for (int mi = 0; mi < 2; ++mi) {
            int mr = mwb + mi * 16 + fr;
            ah[mi] = *(const short8*)&sA[mr][q * 8];
            al[mi] = *(const short8*)&sA[64 + mr][q * 8];
        }
#pragma unroll
        for (int ni = 0; ni < 2; ++ni) {
            int nr = nwb + ni * 16 + fr;
            bh[ni] = *(const short8*)&sB[nr][q * 8];
            bl[ni] = *(const short8*)&sB[64 + nr][q * 8];
        }
#pragma unroll
        for (int mi = 0; mi < 2; ++mi)
#pragma unroll
            for (int ni = 0; ni < 2; ++ni) {
                acc[mi][ni] = __builtin_amdgcn_mfma_f32_16x16x32_bf16(ah[mi], bh[ni], acc[mi][ni], 0, 0, 0);
                acc[mi][ni] = __builtin_amdgcn_mfma_f32_16x16x32_bf16(ah[mi], bl[ni], acc[mi][ni], 0, 0, 0);
                acc[mi][ni] = __builtin_amdgcn_mfma_f32_16x16x32_bf16(al[mi], bh[ni], acc[mi][ni], 0, 0, 0);
            }
        __syncthreads();
    }

#pragma unroll
    for (int mi = 0; mi < 2; ++mi)
#pragma unroll
        for (int ni = 0; ni < 2; ++ni) {
            int n = n0 + nwb + ni * 16 + fr;
            if (n < 256) {
                float bd = b_dt[n];
#pragma unroll
                for (int r = 0; r < 4; ++r) {
                    int m = m0 + mwb + mi * 16 + q * 4 + r;
                    float a2 = acc[mi][ni][r] + bd;
                    float sp = fmaxf(a2, 0.f) + __logf(1.f + __expf(-fabsf(a2)));
                    dt[(size_t)m * DI + n] = sp;
                }
            } else if (n < 288) {
#pragma unroll
                for (int r = 0; r < 4; ++r) {
                    int m = m0 + mwb + mi * 16 + q * 4 + r;
                    bc[(size_t)m * 32 + (n - 256)] = acc[mi][ni][r];
                }
            }
        }
}

// ---------------- scan phase A ----------------
__global__ __launch_bounds__(256) void scan_a_k(const float* __restrict__ dt,
                                                const float* __restrict__ xc,
                                                const float* __restrict__ bc,
                                                const float* __restrict__ A_log,
                                                float* __restrict__ Pst,
                                                float* __restrict__ Fst) {
    __shared__ float Bl[LCHUNK][16];
    const int blk   = blockIdx.x;
    const int b     = blk / NCHUNK;
    const int chunk = blk % NCHUNK;
    const int d     = threadIdx.x;
    const int l0    = chunk * LCHUNK;

    if (d < LCHUNK * 4) {
        int l = d >> 2, q = d & 3;
        *(float4*)(&Bl[l][q * 4]) =
            *(const float4*)(bc + (size_t)(b * LSEQ + l0 + l) * 32 + q * 4);
    }
    float Ads[16];
#pragma unroll
    for (int s = 0; s < 16; ++s) Ads[s] = -expf(A_log[d * DS + s]);
    __syncthreads();

    float h[16], P[16];
#pragma unroll
    for (int s = 0; s < 16; ++s) { h[s] = 0.f; P[s] = 1.f; }

    const float* dtp = dt + ((size_t)b * LSEQ + l0) * DI + d;
    const float* xcp = xc + ((size_t)b * LSEQ + l0) * DI + d;

#pragma unroll 4
    for (int i = 0; i < LCHUNK; ++i) {
        float dtv = dtp[(size_t)i * DI];
        float xcv = xcp[(size_t)i * DI];
        float du  = dtv * xcv;
        float4 b0 = *(float4*)(&Bl[i][0]);
        float4 b1 = *(float4*)(&Bl[i][4]);
        float4 b2 = *(float4*)(&Bl[i][8]);
        float4 b3 = *(float4*)(&Bl[i][12]);
        float bv[16] = {b0.x,b0.y,b0.z,b0.w, b1.x,b1.y,b1.z,b1.w,
                        b2.x,b2.y,b2.z,b2.w, b3.x,b3.y,b3.z,b3.w};
#pragma unroll
        for (int s = 0; s < 16; ++s) {
            float a = __expf(dtv * Ads[s]);
            h[s] = fmaf(h[s], a, du * bv[s]);
            P[s] *= a;
        }
    }
    size_t base = ((size_t)(b * DI + d) * NCHUNK + chunk) * DS;
#pragma unroll
    for (int q = 0; q < 4; ++q) {
        *(float4*)(Pst + base + q * 4) = make_float4(P[q*4], P[q*4+1], P[q*4+2], P[q*4+3]);
        *(float4*)(Fst + base + q * 4) = make_float4(h[q*4], h[q*4+1], h[q*4+2], h[q*4+3]);
    }
}

// ---------------- scan phase B ----------------
__global__ __launch_bounds__(256) void scan_b_k(const float* __restrict__ Pst,
                                                float* __restrict__ Fst) {
    const int t = blockIdx.x * 256 + threadIdx.x;
    const int s = t & 15;
    const int d = (t >> 4) & (DI - 1);
    const int b = t >> 12;
    size_t base = ((size_t)(b * DI + d) * NCHUNK) * DS + s;
    float st = 0.f;
#pragma unroll 8
    for (int c = 0; c < NCHUNK; ++c) {
        size_t idx = base + (size_t)c * DS;
        float P = Pst[idx];
        float F = Fst[idx];
        Fst[idx] = st;
        st = fmaf(P, st, F);
    }
}

// ---------------- scan phase C ----------------
__global__ __launch_bounds__(256) void scan_c_k(const float* __restrict__ dt,
                                                const float* __restrict__ xc,
                                                const float* __restrict__ bc,
                                                const float* __restrict__ xz,
                                                const float* __restrict__ A_log,
                                                const float* __restrict__ Dw,
                                                const float* __restrict__ carry,
                                                float* __restrict__ y) {
    __shared__ float BC[LCHUNK][32];
    const int blk   = blockIdx.x;
    const int b     = blk / NCHUNK;
    const int chunk = blk % NCHUNK;
    const int d     = threadIdx.x;
    const int l0    = chunk * LCHUNK;

    if (d < LCHUNK * 8) {
        int l = d >> 3, q = d & 7;
        *(float4*)(&BC[l][q * 4]) =
            *(const float4*)(bc + (size_t)(b * LSEQ + l0 + l) * 32 + q * 4);
    }
    float Ads[16];
#pragma unroll
    for (int s = 0; s < 16; ++s) Ads[s] = -expf(A_log[d * DS + s]);
    const float Dd = Dw[d];

    float h[16];
    size_t cbase = ((size_t)(b * DI + d) * NCHUNK + chunk) * DS;
#pragma unroll
    for (int q = 0; q < 4; ++q) {
        float4 c4 = *(const float4*)(carry + cbase + q * 4);
        h[q*4] = c4.x; h[q*4+1] = c4.y; h[q*4+2] = c4.z; h[q*4+3] = c4.w;
    }
    __syncthreads();

    const float* dtp = dt + ((size_t)b * LSEQ + l0) * DI + d;
    const float* xcp = xc + ((size_t)b * LSEQ + l0) * DI + d;
    const float* zp  = xz + ((size_t)b * LSEQ + l0) * NIN + DI + d;
    float* yout      = y  + ((size_t)b * LSEQ + l0) * DI + d;

#pragma unroll 4
    for (int i = 0; i < LCHUNK; ++i) {
        float dtv = dtp[(size_t)i * DI];
        float xcv = xcp[(size_t)i * DI];
        float zv  = zp[(size_t)i * NIN];
        float du  = dtv * xcv;
        float4 b0 = *(float4*)(&BC[i][0]);
        float4 b1 = *(float4*)(&BC[i][4]);
        float4 b2 = *(float4*)(&BC[i][8]);
        float4 b3 = *(float4*)(&BC[i][12]);
        float4 c0 = *(float4*)(&BC[i][16]);
        float4 c1 = *(float4*)(&BC[i][20]);
        float4 c2 = *(float4*)(&BC[i][24]);
        float4 c3 = *(float4*)(&BC[i][28]);
        float bv[16] = {b0.x,b0.y,b0.z,b0.w, b1.x,b1.y,b1.z,b1.w,
                        b2.x,b2.y,b2.z,b2.w, b3.x,b3.y,b3.z,b3.w};
        float cv[16] = {c0.x,c0.y,c0.z,c0.w, c1.x,c1.y,c1.z,c1.w,
                        c2.x,c2.y,c2.z,c2.w, c3.x,c3.y,c3.z,c3.w};
        float yv = 0.f;
#pragma unroll
        for (int s = 0; s < 16; ++s) {
            float a = __expf(dtv * Ads[s]);
            h[s] = fmaf(h[s], a, du * bv[s]);
            yv = fmaf(h[s], cv[s], yv);
        }
        float yf = fmaf(xcv, Dd, yv);
        yout[(size_t)i * DI] = yf * (zv * sigmoid_f(zv));
    }
}

// ---------------- gemm_out (MFMA bf16x3): out[b,c,l] = sum_d y[b,l,d] * W_out[d,c] ----------------
__global__ __launch_bounds__(256) void gemm_out_k(const float* __restrict__ y,
                                                  const unsigned short* __restrict__ WT_hi,
                                                  const unsigned short* __restrict__ WT_lo,
                                                  float* __restrict__ out) {
    __shared__ unsigned short sA[128][40];
    __shared__ unsigned short sB[128][40];
    const int b  = blockIdx.z;
    const int m0 = blockIdx.y * 64;    // l
    const int n0 = blockIdx.x * 64;    // c
    const int t  = threadIdx.x;
    const int w    = t >> 6;
    const int lane = t & 63;
    const int mwb = (w & 1) * 32;
    const int nwb = (w >> 1) * 32;
    const int fr  = lane & 15;
    const int q   = lane >> 4;

    const int row = t >> 2;
    const int kq8 = (t & 3) * 8;

    floatx4 acc[2][2];
#pragma unroll
    for (int mi = 0; mi < 2; ++mi)
#pragma unroll
        for (int ni = 0; ni < 2; ++ni) acc[mi][ni] = (floatx4){0.f, 0.f, 0.f, 0.f};

    for (int k0 = 0; k0 < DI; k0 += 32) {
        {
            const float* pa = y + ((size_t)b * LSEQ + m0 + row) * DI + k0 + kq8;
            float v[8];
            *(float4*)(v)     = *(const float4*)(pa);
            *(float4*)(v + 4) = *(const float4*)(pa + 4);
            short8 hi, lo;
#pragma unroll
            for (int j = 0; j < 8; ++j) {
                unsigned int h = bf16_rne(v[j]);
                float r = v[j] - __uint_as_float(h << 16);
                hi[j] = (short)h;
                lo[j] = (short)bf16_rne(r);
            }
            *(short8*)&sA[row][kq8]      = hi;
            *(short8*)&sA[64 + row][kq8] = lo;

            const size_t boff = (size_t)(n0 + row) * DM + k0 + kq8;
            *(short8*)&sB[row][kq8]      = *(const short8*)(WT_hi + boff);
            *(short8*)&sB[64 + row][kq8] = *(const short8*)(WT_lo + boff);
        }
        __syncthreads();

        short8 ah[2], al[2], bh[2], bl[2];
#pragma unroll
        for (int mi = 0; mi < 2; ++mi) {
            int mr = mwb + mi * 16 + fr;
            ah[mi] = *(const short8*)&sA[mr][q * 8];
            al[mi] = *(const short8*)&sA[64 + mr][q * 8];
        }
#pragma unroll
        for (int ni = 0; ni < 2; ++ni) {
            int nr = nwb + ni * 16 + fr;
            bh[ni] = *(const short8*)&sB[nr][q * 8];
            bl[ni] = *(const short8*)&sB[64 + nr][q * 8];
        }
#pragma unroll
        for (int mi = 0; mi < 2; ++mi)
#pragma unroll
            for (int ni = 0; ni < 2; ++ni) {
                acc[mi][ni] = __builtin_amdgcn_mfma_f32_16x16x32_bf16(ah[mi], bh[ni], acc[mi][ni], 0, 0, 0);
                acc[mi][ni] = __builtin_amdgcn_mfma_f32_16x16x32_bf16(ah[mi], bl[ni], acc[mi][ni], 0, 0, 0);
                acc[mi][ni] = __builtin_amdgcn_mfma_f32_16x16x32_bf16(al[mi], bh[ni], acc[mi][ni], 0, 0, 0);
            }
        __syncthreads();
    }

#pragma unroll
    for (int mi = 0; mi < 2; ++mi)
#pragma unroll
        for (int ni = 0; ni < 2; ++ni) {
            int c = n0 + nwb + ni * 16 + fr;
            float* op = out + ((size_t)b * DM + c) * LSEQ + m0 + mwb + mi * 16 + q * 4;
            *(float4*)op = make_float4(acc[mi][ni][0], acc[mi][ni][1],
                                       acc[mi][ni][2], acc[mi][ni][3]);
        }
}

extern "C" void kernel_launch(void* const* d_in, const int* in_sizes, int n_in,
                              void* d_out, int out_size, void* d_ws, size_t ws_size,
                              hipStream_t stream) {
    const float* x      = (const float*)d_in[0];
    const float* W_in   = (const float*)d_in[1];
    const float* conv_w = (const float*)d_in[2];
    const float* conv_b = (const float*)d_in[3];
    const float* W_x    = (const float*)d_in[4];
    const float* W_dt   = (const float*)d_in[5];
    const float* b_dt   = (const float*)d_in[6];
    const float* A_log  = (const float*)d_in[7];
    const float* Dw     = (const float*)d_in[8];
    const float* W_out  = (const float*)d_in[9];
    float* out = (float*)d_out;

    float* ws   = (float*)d_ws;
    float* xz   = ws;                    // B*L*512            = 4,194,304
    float* xc   = xz + 4194304;          // B*L*256            = 2,097,152
    float* bc   = xc + 2097152;          // B*L*32             =   262,144
    float* dtb  = bc + 262144;           // B*L*256            = 2,097,152
    float* Pst  = dtb + 2097152;         // B*DI*NCHUNK*DS     = 2,097,152
    float* Fst  = Pst + 2097152;         // 2,097,152 (carry in-place)
    float* yb   = Fst + 2097152;         // B*L*DI             = 2,097,152
    unsigned short* WinT_hi  = (unsigned short*)(yb + 2097152);   // 512*256
    unsigned short* WinT_lo  = WinT_hi + 131072;
    unsigned short* WoutT_hi = WinT_lo + 131072;                  // 256*256
    unsigned short* WoutT_lo = WoutT_hi + 65536;
    unsigned short* BcatT_hi = WoutT_lo + 65536;                  // 320*256
    unsigned short* BcatT_lo = BcatT_hi + 81920;

    wsplit_k   <<<dim3(256), 512, 0, stream>>>(W_in, W_out, WinT_hi, WinT_lo, WoutT_hi, WoutT_lo);
    bcat_k     <<<dim3(256), 320, 0, stream>>>(W_x, W_dt, BcatT_hi, BcatT_lo);
    gemm_in_k  <<<dim3(8, 64, BSZ), 256, 0, stream>>>(x, WinT_hi, WinT_lo, xz);
    conv_silu_k<<<dim3(BSZ * LSEQ / 4), 256, 0, stream>>>(xz, conv_w, conv_b, xc);
    gemm_x2_k  <<<dim3(5, 128), 256, 0, stream>>>(xc, BcatT_hi, BcatT_lo, b_dt, dtb, bc);
    scan_a_k   <<<dim3(BSZ * NCHUNK), 256, 0, stream>>>(dtb, xc, bc, A_log, Pst, Fst);
    scan_b_k   <<<dim3(BSZ * DI * DS / 256), 256, 0, stream>>>(Pst, Fst);
    scan_c_k   <<<dim3(BSZ * NCHUNK), 256, 0, stream>>>(dtb, xc, bc, xz, A_log, Dw, Fst, yb);
    gemm_out_k <<<dim3(4, 64, BSZ), 256, 0, stream>>>(yb, WoutT_hi, WoutT_lo, out);
}